// Round 5
// baseline (1667.009 us; speedup 1.0000x reference)
//
#include <hip/hip_runtime.h>
#include <hip/hip_bf16.h>
#include <stdint.h>

typedef unsigned int uint_t;
typedef unsigned short ushort_t;

#define NN 100000
#define EE 1600000
#define CC 25000
#define DINTER 144
#define NBKT 196          // C-side coarse buckets: src cluster >> 7
#define NBKT2 1568        // A-side buckets: (src_node/12500)*196 + (dst_cluster>>7)

// ---- ws layout in 32-bit words ----
#define W_M1B      0u         // u16 [131*128] bf16 m1 = 8384 words
#define W_NEWPOS   8384u      // f32 [25000*4] -> 108384
#define W_AGGB     108384u    // bf16[25000*132] = 1,650,000 words -> 1,758,384
#define W_PAGG     1758384u   // bf16[8][25000*132] = 13,200,000 words -> 14,958,384
#define W_PKA4     14958384u  // uint4[1,600,000] = 6,400,000 words -> 21,358,384 (16B-aligned)
#define W_PKC      21358384u  // u32 [1600000] -> 22,958,384
#define W_BHA2     22958384u  // u32 [1568]
#define W_BHC      22959952u  // u32 [196]   (adjacent to BHA2: one memset of 1764)
#define W_BBA2     22960148u  // u32 [1569]
#define W_BCURA2   22961717u  // u32 [1568]
#define W_BBC      22963285u  // u32 [197]
#define W_BCURC    22963482u  // u32 [196]
#define W_BCNTC    22963678u  // u32 [1568]
#define W_EBASE    22965246u  // u32 [1569]
#define WS_WORDS   22966815u  // 91.9 MB (round-0 kernel used 92.3 MB successfully)

// ---- out layout in FLOAT32 elements (total 11,300,000) ----
#define O_XNEW  0u
#define O_POS   3200000u
#define O_EI    3275000u
#define O_ATTR  6475000u
#define O_BATCH 11275000u
// x_bf16 staging: first 6.4M words of the O_EI region (re-zeroed before enc_emit)

static __device__ __forceinline__ uint_t f2bf(float f) {
    union { float f; uint_t i; } v; v.f = f;
    uint_t x = v.i;
    return (x + 0x7fffu + ((x >> 16) & 1u)) >> 16;  // RNE
}
static __device__ __forceinline__ float bf2f(ushort_t u) {
    union { uint_t i; float f; } v; v.i = ((uint_t)u) << 16; return v.f;
}

// K0: pack x (f32) -> bf16x2 words into the output-staging region.
__global__ void xpack(const float4* __restrict__ x4, uint2* __restrict__ xb2) {
    int i = blockIdx.x * 256 + threadIdx.x;
    if (i >= NN * 32) return;            // 12.8M floats / 4
    float4 v = x4[i];
    uint2 r;
    r.x = f2bf(v.x) | (f2bf(v.y) << 16);
    r.y = f2bf(v.z) | (f2bf(v.w) << 16);
    xb2[i] = r;
}

// K1: M1[j][o] = sum_f Wrow_j[f] * Wg[f][o], emitted directly as bf16.
__global__ void build_m1f(const float* __restrict__ Wconv,
                          const float* __restrict__ Wedge,
                          const float* __restrict__ Wg,
                          ushort_t* __restrict__ m1b) {
    int j = blockIdx.x;   // 0..130
    int o = threadIdx.x;  // 0..127
    const float* wrow = (j < 128) ? (Wconv + j * DINTER + 16)
                                  : (Wedge + (j - 128) * DINTER + 16);
    float acc = 0.f;
    for (int f = 0; f < 128; ++f)
        acc += wrow[f] * Wg[f * 128 + o];
    m1b[j * 128 + o] = (ushort_t)f2bf(acc);
}

// K2a: fused coarse histograms (LDS-aggregated).
// hA2: (src_slice, dst cluster >> 7) for the XCD-affine reduce.  hC: src cluster >> 7 (dedupe).
__global__ void edge_hist2(const int* __restrict__ ei,
                           uint_t* __restrict__ bhA2, uint_t* __restrict__ bhC) {
    __shared__ uint_t hA[NBKT2], hC[NBKT];
    int tid = threadIdx.x;
    for (int i = tid; i < NBKT2; i += 256) hA[i] = 0;
    for (int i = tid; i < NBKT; i += 256) hC[i] = 0;
    __syncthreads();
    for (int e = blockIdx.x * 256 + tid; e < EE; e += 256 * 256) {
        uint_t u = (uint_t)ei[e];
        uint_t v = (uint_t)ei[EE + e];
        atomicAdd(&hA[(u / 12500u) * 196u + (v >> 9)], 1u);
        atomicAdd(&hC[u >> 9], 1u);
    }
    __syncthreads();
    for (int i = tid; i < NBKT2; i += 256) if (hA[i]) atomicAdd(&bhA2[i], hA[i]);
    for (int i = tid; i < NBKT; i += 256)  if (hC[i]) atomicAdd(&bhC[i], hC[i]);
}

// Single-block exclusive scan. out[0..n] (out[n]=total), optional copy out2[0..n-1].
__global__ void scan_small(const uint_t* __restrict__ in, uint_t* __restrict__ out,
                           uint_t* __restrict__ out2, int n) {
    __shared__ uint_t part[256];
    int tid = threadIdx.x;
    int per = (n + 255) >> 8;
    int lo = tid * per;
    int hi = lo + per; if (hi > n) hi = n;
    if (lo > n) lo = n;
    uint_t s = 0;
    for (int i = lo; i < hi; ++i) s += in[i];
    part[tid] = s;
    __syncthreads();
    for (int off = 1; off < 256; off <<= 1) {
        uint_t v = (tid >= off) ? part[tid - off] : 0u;
        __syncthreads();
        part[tid] += v;
        __syncthreads();
    }
    uint_t run = part[tid] - s;
    for (int i = lo; i < hi; ++i) {
        out[i] = run;
        if (out2) out2[i] = run;
        run += in[i];
    }
    if (tid == 255) out[n] = run;
}

#define TPB 4096
// K2b: bucket scatter for the reduce. Payload uint4 = {(cl<<17)|src, ea.x, ea.y, ea.z}
// so the reduce never gathers ei[] or ea[] (both read COALESCED here). Tile-private
// run reservation -> write fronts (1568 x 64B) stay L2-resident -> ~1x writeback.
__global__ void bucket_place_A2(const int* __restrict__ ei, const float* __restrict__ ea,
                                uint_t* __restrict__ bcur, uint4* __restrict__ pk4) {
    __shared__ uint_t hist[NBKT2], gbase[NBKT2], cur[NBKT2];
    int tid = threadIdx.x;
    int t0 = blockIdx.x * TPB;
    int nt = EE - t0; if (nt > TPB) nt = TPB;
    for (int i = tid; i < NBKT2; i += 256) { hist[i] = 0; cur[i] = 0; }
    __syncthreads();
    for (int i = tid; i < nt; i += 256) {
        int e = t0 + i;
        uint_t u = (uint_t)ei[e];
        uint_t v = (uint_t)ei[EE + e];
        atomicAdd(&hist[(u / 12500u) * 196u + (v >> 9)], 1u);
    }
    __syncthreads();
    for (int b = tid; b < NBKT2; b += 256) {
        uint_t h = hist[b];
        if (h) gbase[b] = atomicAdd(&bcur[b], h);
    }
    __syncthreads();
    for (int i = tid; i < nt; i += 256) {
        int e = t0 + i;
        uint_t u = (uint_t)ei[e];
        uint_t v = (uint_t)ei[EE + e];
        uint_t b = (u / 12500u) * 196u + (v >> 9);
        uint_t r = gbase[b] + atomicAdd(&cur[b], 1u);
        uint4 p;
        p.x = (((v >> 2) & 127u) << 17) | u;
        p.y = __float_as_uint(ea[(size_t)e * 3 + 0]);
        p.z = __float_as_uint(ea[(size_t)e * 3 + 1]);
        p.w = __float_as_uint(ea[(size_t)e * 3 + 2]);
        pk4[r] = p;
    }
}

// K2b': dedupe-side bucket scatter; full key (u<<15)|v fits u32, bucket = pk>>22.
__global__ void bucket_place_C(const int* __restrict__ ei, uint_t* __restrict__ bcur,
                               uint_t* __restrict__ pkC) {
    __shared__ uint_t pk[TPB];
    __shared__ uint_t gpk[TPB];
    __shared__ uint_t hist[NBKT], lbase[NBKT], gbase[NBKT], cur[NBKT];
    __shared__ uint_t part[256];
    int tid = threadIdx.x;
    int t0 = blockIdx.x * TPB;
    int nt = EE - t0; if (nt > TPB) nt = TPB;
    for (int i = tid; i < NBKT; i += 256) { hist[i] = 0; cur[i] = 0; }
    __syncthreads();
    for (int i = tid; i < nt; i += 256) {
        int e = t0 + i;
        uint_t u = ((uint_t)ei[e]) >> 2;
        uint_t v = ((uint_t)ei[EE + e]) >> 2;
        uint_t w = (u << 15) | v;
        pk[i] = w;
        atomicAdd(&hist[w >> 22], 1u);
    }
    __syncthreads();
    uint_t h = (tid < NBKT) ? hist[tid] : 0u;
    if (tid < NBKT) gbase[tid] = atomicAdd(&bcur[tid], h);
    part[tid] = h;
    __syncthreads();
    for (int off = 1; off < 256; off <<= 1) {
        uint_t v = (tid >= off) ? part[tid - off] : 0u;
        __syncthreads();
        part[tid] += v;
        __syncthreads();
    }
    if (tid < NBKT) lbase[tid] = part[tid] - h;
    __syncthreads();
    for (int i = tid; i < nt; i += 256) {
        uint_t b = pk[i] >> 22;
        uint_t r = lbase[b] + atomicAdd(&cur[b], 1u);
        gpk[r] = pk[i];
    }
    __syncthreads();
    for (int r = tid; r < nt; r += 256) {
        uint_t b = gpk[r] >> 22;
        pkC[gbase[b] + ((uint_t)r - lbase[b])] = gpk[r];
    }
}

// K3: per cluster: new_pos (f32 ws + f32 out), new_batch.
__global__ void cluster_pass(const float* __restrict__ pos, const int* __restrict__ batch,
                             float* __restrict__ newpos, float* __restrict__ out) {
    int c = blockIdx.x * 256 + threadIdx.x;
    if (c >= CC) return;
    float px = 0.f, py = 0.f, pz = 0.f;
    for (int j = 0; j < 4; ++j) {
        int n = c * 4 + j;
        px += pos[n * 3 + 0];
        py += pos[n * 3 + 1];
        pz += pos[n * 3 + 2];
    }
    px *= 0.25f; py *= 0.25f; pz *= 0.25f;
    newpos[c * 4 + 0] = px; newpos[c * 4 + 1] = py; newpos[c * 4 + 2] = pz;
    out[O_POS + c * 3 + 0] = px;
    out[O_POS + c * 3 + 1] = py;
    out[O_POS + c * 3 + 2] = pz;
    int b = batch[c * 4];
    b = max(b, batch[c * 4 + 1]);
    b = max(b, batch[c * 4 + 2]);
    b = max(b, batch[c * 4 + 3]);
    out[O_BATCH + c] = (float)b;
}

// K2d: XCD-affine partial reduce. Block -> bucket (s, cb) with s = blockIdx%8 so all
// gathers of x-slice s (12500 rows = 3.2 MB, fits 4 MB private L2) run on XCD s
// (blockIdx round-robins across the 8 XCDs). f32 LDS accumulator over the bucket's
// 128 clusters; writes bf16 partials pagg[s][c][132]. src+ea come from the payload —
// no ei/ea gather. Each (s,cb) block writes ALL its rows (zeros incl.) -> no memset.
__global__ void cluster_reduce2(const uint_t* __restrict__ bbA2, const uint4* __restrict__ pk4,
                                const uint_t* __restrict__ xb, ushort_t* __restrict__ pagg) {
    __shared__ float acc[128 * 132];    // 67.6 KB -> 2 blocks/CU
    int tid = threadIdx.x;
    int lane = tid & 63;
    int s = blockIdx.x & 7;
    int q = blockIdx.x >> 3;            // cb 0..195
    int bkt = s * 196 + q;
    uint_t start = bbA2[bkt], end = bbA2[bkt + 1];
    for (int i = tid; i < 128 * 132; i += 256) acc[i] = 0.f;
    __syncthreads();
    for (uint_t base = start + (uint_t)(tid >> 6) * 64u; base < end; base += 256u) {
        uint_t idx2 = base + (uint_t)lane;
        int nm = (int)min(64u, end - base);
        uint_t w = 0;
        if (idx2 < end) {
            uint4 p = pk4[idx2];
            w = p.x;
            uint_t cl = w >> 17;
            atomicAdd(&acc[cl * 132 + 128], __uint_as_float(p.y));
            atomicAdd(&acc[cl * 132 + 129], __uint_as_float(p.z));
            atomicAdd(&acc[cl * 132 + 130], __uint_as_float(p.w));
        }
        if (nm == 64) {
            #pragma unroll 8
            for (int j = 0; j < 64; ++j) {
                uint_t wj = (uint_t)__shfl((int)w, j, 64);
                uint_t src = wj & 0x1FFFFu;
                uint_t cl = wj >> 17;
                uint_t xv = xb[(size_t)src * 64 + lane];
                atomicAdd(&acc[cl * 132 + 2 * lane],     bf2f((ushort_t)(xv & 0xffffu)));
                atomicAdd(&acc[cl * 132 + 2 * lane + 1], bf2f((ushort_t)(xv >> 16)));
            }
        } else {
            for (int j = 0; j < nm; ++j) {
                uint_t wj = (uint_t)__shfl((int)w, j, 64);
                uint_t src = wj & 0x1FFFFu;
                uint_t cl = wj >> 17;
                uint_t xv = xb[(size_t)src * 64 + lane];
                atomicAdd(&acc[cl * 132 + 2 * lane],     bf2f((ushort_t)(xv & 0xffffu)));
                atomicAdd(&acc[cl * 132 + 2 * lane + 1], bf2f((ushort_t)(xv >> 16)));
            }
        }
    }
    __syncthreads();
    int c0 = q * 128;
    for (int i = tid; i < 128 * 66; i += 256) {
        int cl = i / 66, wd = i - cl * 66;
        int c = c0 + cl;
        if (c < CC) {
            uint_t v = f2bf(acc[cl * 132 + 2 * wd]) | (f2bf(acc[cl * 132 + 2 * wd + 1]) << 16);
            *(uint_t*)(pagg + ((size_t)s * 25000u + (uint_t)c) * 132 + 2 * wd) = v;
        }
    }
}

// K2e: fold 8 slice-partials -> aggb (f32 sum of bf16 partials, bf16 out).
__global__ void agg_merge(const uint_t* __restrict__ paggw, uint_t* __restrict__ aggw) {
    int j = blockIdx.x * 256 + threadIdx.x;
    if (j >= 1650000) return;
    float lo = 0.f, hi = 0.f;
    #pragma unroll
    for (int s = 0; s < 8; ++s) {
        uint_t w = paggw[(size_t)s * 1650000u + (uint_t)j];
        lo += bf2f((ushort_t)(w & 0xffffu));
        hi += bf2f((ushort_t)(w >> 16));
    }
    aggw[j] = f2bf(lo) | (f2bf(hi) << 16);
}

// K4: x_new[c][o] = 0.25 * sum_{j<131} aggb[c][j] * M1[j][o].
#define GEMM_CPB 32   // clusters per block = 4 iterations of 8
__global__ void gemm_tiled(const ushort_t* __restrict__ aggb, const ushort_t* __restrict__ m1b,
                           float* __restrict__ out) {
    __shared__ ushort_t m1s[131 * 128];            // 33.5 KB bf16
    __shared__ __align__(16) float srowT[132][8];  // 4.2 KB, [j][cluster-in-group]
    int tid = threadIdx.x;
    {
        const uint_t* m1w = (const uint_t*)m1b;
        uint_t* m1sw = (uint_t*)m1s;
        for (int i = tid; i < 131 * 64; i += 256) m1sw[i] = m1w[i];
    }
    int o = tid & 127, half = tid >> 7;
    int c0b = blockIdx.x * GEMM_CPB;
    const uint_t* aggw = (const uint_t*)aggb;      // row = 66 u32 words
    for (int it = 0; it < GEMM_CPB / 8; ++it) {
        int c0 = c0b + it * 8;
        __syncthreads();   // previous-iteration readers done before overwrite
        for (int i = tid; i < 528; i += 256) {
            int cg = i / 66, rem = i - cg * 66;
            int c = c0 + cg;
            uint_t w = (c < CC) ? aggw[(size_t)c * 66 + rem] : 0u;
            srowT[rem * 2][cg]     = bf2f((ushort_t)(w & 0xffffu));
            srowT[rem * 2 + 1][cg] = bf2f((ushort_t)(w >> 16));
        }
        __syncthreads();   // also covers m1s staging on it==0
        float acc0 = 0.f, acc1 = 0.f, acc2 = 0.f, acc3 = 0.f;
        #pragma unroll 4
        for (int j = 0; j < 131; ++j) {
            float m = bf2f(m1s[j * 128 + o]);
            float4 s = *(const float4*)&srowT[j][half * 4];  // broadcast within wave
            acc0 += s.x * m;
            acc1 += s.y * m;
            acc2 += s.z * m;
            acc3 += s.w * m;
        }
        int cb = c0 + half * 4;
        if (cb + 0 < CC) out[O_XNEW + (size_t)(cb + 0) * 128 + o] = 0.25f * acc0;
        if (cb + 1 < CC) out[O_XNEW + (size_t)(cb + 1) * 128 + o] = 0.25f * acc1;
        if (cb + 2 < CC) out[O_XNEW + (size_t)(cb + 2) * 128 + o] = 0.25f * acc2;
        if (cb + 3 < CC) out[O_XNEW + (size_t)(cb + 3) * 128 + o] = 0.25f * acc3;
    }
}

// K6a: per-(bucket,sub) unique-(u,v) counts via 50 KB LDS bitmap (16 u-clusters x
// 25000 v bits). Grid = NBKT*8 — one block per sub-round.
__global__ void enc_count(const uint_t* __restrict__ bbC, const uint_t* __restrict__ pkC,
                          uint_t* __restrict__ bcnt) {
    __shared__ uint_t bmp[12500];
    __shared__ uint_t red[256];
    int tid = threadIdx.x;
    int bk = blockIdx.x >> 3;
    uint_t sub = (uint_t)(blockIdx.x & 7);
    uint_t s = bbC[bk], epos = bbC[bk + 1];
    int n = (int)(epos - s);
    for (int i = tid; i < 12500; i += 256) bmp[i] = 0;
    __syncthreads();
    for (int i = tid; i < n; i += 256) {
        uint_t w = pkC[s + i];
        if (((w >> 19) & 7u) == sub) {
            uint_t le = ((w >> 15) & 15u) * 25000u + (w & 32767u);
            atomicOr(&bmp[le >> 5], 1u << (le & 31u));
        }
    }
    __syncthreads();
    uint_t cnt = 0;
    for (int i = tid; i < 12500; i += 256) cnt += __popc(bmp[i]);
    red[tid] = cnt;
    __syncthreads();
    for (int off = 128; off; off >>= 1) {
        if (tid < off) red[tid] += red[tid + off];
        __syncthreads();
    }
    if (tid == 0) bcnt[blockIdx.x] = red[0];
}

// K6b: rebuild the (bucket,sub) LDS bitmap, rank via block scan, emit new edges +
// attrs in ascending enc order (bk asc, sub asc, word asc, bit asc == (u,v) lex asc).
__global__ void enc_emit(const uint_t* __restrict__ bbC, const uint_t* __restrict__ pkC,
                         const uint_t* __restrict__ ebase, const float* __restrict__ newpos,
                         float* __restrict__ out) {
    __shared__ uint_t bmp[12500];
    __shared__ uint_t sh[256];
    int tid = threadIdx.x;
    int bk = blockIdx.x >> 3;
    uint_t sub = (uint_t)(blockIdx.x & 7);
    uint_t s = bbC[bk], epos = bbC[bk + 1];
    int n = (int)(epos - s);
    int lo = tid * 49, hi = lo + 49; if (hi > 12500) hi = 12500;
    for (int i = tid; i < 12500; i += 256) bmp[i] = 0;
    __syncthreads();
    for (int i = tid; i < n; i += 256) {
        uint_t w = pkC[s + i];
        if (((w >> 19) & 7u) == sub) {
            uint_t le = ((w >> 15) & 15u) * 25000u + (w & 32767u);
            atomicOr(&bmp[le >> 5], 1u << (le & 31u));
        }
    }
    __syncthreads();
    uint_t mine = 0;
    for (int i = lo; i < hi; ++i) mine += __popc(bmp[i]);
    sh[tid] = mine;
    __syncthreads();
    for (int off = 1; off < 256; off <<= 1) {
        uint_t v = (tid >= off) ? sh[tid - off] : 0u;
        __syncthreads();
        sh[tid] += v;
        __syncthreads();
    }
    uint_t rank = ebase[blockIdx.x] + sh[tid] - mine;
    uint_t ubase = (uint_t)bk * 128u + sub * 16u;
    for (int i = lo; i < hi; ++i) {
        uint_t bits = bmp[i];
        while (bits) {
            int b = __builtin_ctz(bits);
            bits &= bits - 1u;
            uint_t le = (uint_t)i * 32u + (uint_t)b;
            uint_t uo = le / 25000u;
            uint_t v = le - uo * 25000u;
            uint_t u = ubase + uo;
            out[O_EI + rank] = (float)u;
            out[O_EI + EE + rank] = (float)v;
            out[O_ATTR + (size_t)rank * 3 + 0] = newpos[v * 4 + 0] - newpos[u * 4 + 0];
            out[O_ATTR + (size_t)rank * 3 + 1] = newpos[v * 4 + 1] - newpos[u * 4 + 1];
            out[O_ATTR + (size_t)rank * 3 + 2] = newpos[v * 4 + 2] - newpos[u * 4 + 2];
            rank++;
        }
    }
}

extern "C" void kernel_launch(void* const* d_in, const int* in_sizes, int n_in,
                              void* d_out, int out_size, void* d_ws, size_t ws_size,
                              hipStream_t stream) {
    const float* x     = (const float*)d_in[0];
    const float* pos   = (const float*)d_in[1];
    const int*   ei    = (const int*)d_in[2];
    const float* ea    = (const float*)d_in[3];
    const int*   batch = (const int*)d_in[4];
    const float* Wconv = (const float*)d_in[5];
    const float* Wedge = (const float*)d_in[6];
    // d_in[7] = D_bloom: dead (bloom_pos never reaches an output)
    const float* Wg    = (const float*)d_in[8];
    // d_in[9] = W_gattr: contribution cancels exactly within each cluster

    float*  out = (float*)d_out;
    uint_t* ws  = (uint_t*)d_ws;

    if (ws_size < (size_t)WS_WORDS * 4) return;

    ushort_t* m1b    = (ushort_t*)(ws + W_M1B);
    float*    newpos = (float*)(ws + W_NEWPOS);
    ushort_t* aggb   = (ushort_t*)(ws + W_AGGB);
    ushort_t* pagg   = (ushort_t*)(ws + W_PAGG);
    uint4*    pk4    = (uint4*)(ws + W_PKA4);
    uint_t*   pkC    = ws + W_PKC;
    uint_t*   bhA2   = ws + W_BHA2;
    uint_t*   bhC    = ws + W_BHC;
    uint_t*   bbA2   = ws + W_BBA2;
    uint_t*   bcurA2 = ws + W_BCURA2;
    uint_t*   bbC    = ws + W_BBC;
    uint_t*   bcurC  = ws + W_BCURC;
    uint_t*   bcntC  = ws + W_BCNTC;
    uint_t*   ebase  = ws + W_EBASE;
    uint_t*   xb     = (uint_t*)(out + O_EI);   // 6.4M-word bf16-x staging in out region

    hipMemsetAsync(bhA2, 0, (size_t)(NBKT2 + NBKT) * 4, stream);   // bhA2 + bhC contiguous

    xpack<<<dim3(12500), dim3(256), 0, stream>>>((const float4*)x, (uint2*)xb);
    build_m1f<<<dim3(131), dim3(128), 0, stream>>>(Wconv, Wedge, Wg, m1b);
    edge_hist2<<<dim3(256), dim3(256), 0, stream>>>(ei, bhA2, bhC);
    scan_small<<<dim3(1), dim3(256), 0, stream>>>(bhA2, bbA2, bcurA2, NBKT2);
    scan_small<<<dim3(1), dim3(256), 0, stream>>>(bhC, bbC, bcurC, NBKT);
    bucket_place_A2<<<dim3((EE + TPB - 1) / TPB), dim3(256), 0, stream>>>(ei, ea, bcurA2, pk4);
    bucket_place_C<<<dim3((EE + TPB - 1) / TPB), dim3(256), 0, stream>>>(ei, bcurC, pkC);
    cluster_pass<<<dim3(98), dim3(256), 0, stream>>>(pos, batch, newpos, out);
    cluster_reduce2<<<dim3(NBKT2), dim3(256), 0, stream>>>(bbA2, pk4, xb, pagg);
    agg_merge<<<dim3(6446), dim3(256), 0, stream>>>((const uint_t*)pagg, (uint_t*)aggb);
    gemm_tiled<<<dim3((CC + GEMM_CPB - 1) / GEMM_CPB), dim3(256), 0, stream>>>(aggb, m1b, out);
    // x_bf16 staging no longer needed: zero the EI/ATTR region (incl. padding tail)
    hipMemsetAsync((char*)d_out + (size_t)O_EI * 4, 0, (size_t)(3200000 + 4800000) * 4, stream);
    enc_count<<<dim3(NBKT * 8), dim3(256), 0, stream>>>(bbC, pkC, bcntC);
    scan_small<<<dim3(1), dim3(256), 0, stream>>>(bcntC, ebase, (uint_t*)0, NBKT * 8);
    enc_emit<<<dim3(NBKT * 8), dim3(256), 0, stream>>>(bbC, pkC, ebase, newpos, out);
}

// Round 6
// 610.796 us; speedup vs baseline: 2.7292x; 2.7292x over previous
//
#include <hip/hip_runtime.h>
#include <hip/hip_bf16.h>
#include <stdint.h>

typedef unsigned int uint_t;
typedef unsigned short ushort_t;

#define NN 100000
#define EE 1600000
#define CC 25000
#define DINTER 144
#define NBKT 196          // C-side coarse buckets: src cluster >> 7
#define NBKT2 1568        // A-side buckets: (src_node/12500)*196 + (dst_node>>9)

// ---- ws layout in 32-bit words (total 92.27 MB <= 92.31 MB proven in round 0) ----
#define W_M1B      0u         // u16 [131*128] bf16 m1 = 8384 words
#define W_AGGB     8384u      // bf16[25000*132] = 1,650,000 words
#define W_PAGG     1658384u   // bf16[8][25000*132] = 13,200,000 words
#define W_PKA4     14858384u  // uint4[1,600,000] = 6,400,000 words (offset %4 == 0)
#define W_PKC      21258384u  // u32 [1600000]
#define W_OFFS2    22858384u  // u32 [200001]  per-(slice,cluster) segment offsets
#define W_BHA2     23058385u  // u32 [1568]
#define W_BHC      23059953u  // u32 [196]   (adjacent to BHA2: one memset of 1764)
#define W_BBA2     23060149u  // u32 [1569]
#define W_BCURA2   23061718u  // u32 [1568]
#define W_BBC      23063286u  // u32 [197]
#define W_BCURC    23063483u  // u32 [196]
#define W_BCNTC    23063679u  // u32 [1568]
#define W_EBASE    23065247u  // u32 [1569]
#define WS_WORDS   23066816u

// ---- out layout in FLOAT32 elements (total 11,300,000) ----
#define O_XNEW  0u
#define O_POS   3200000u
#define O_EI    3275000u
#define O_ATTR  6475000u
#define O_BATCH 11275000u
// x_bf16 staging: first 6.4M words of the O_EI region (re-zeroed before enc_emit)
// new_pos f32[25000*3] lives at out[O_POS] and is read back by enc_emit.

static __device__ __forceinline__ uint_t f2bf(float f) {
    union { float f; uint_t i; } v; v.f = f;
    uint_t x = v.i;
    return (x + 0x7fffu + ((x >> 16) & 1u)) >> 16;  // RNE
}
static __device__ __forceinline__ float bf2f(ushort_t u) {
    union { uint_t i; float f; } v; v.i = ((uint_t)u) << 16; return v.f;
}

// K0: pack x (f32) -> bf16x2 words into the output-staging region.
__global__ void xpack(const float4* __restrict__ x4, uint2* __restrict__ xb2) {
    int i = blockIdx.x * 256 + threadIdx.x;
    if (i >= NN * 32) return;            // 12.8M floats / 4
    float4 v = x4[i];
    uint2 r;
    r.x = f2bf(v.x) | (f2bf(v.y) << 16);
    r.y = f2bf(v.z) | (f2bf(v.w) << 16);
    xb2[i] = r;
}

// K1: M1[j][o] = sum_f Wrow_j[f] * Wg[f][o], emitted directly as bf16.
__global__ void build_m1f(const float* __restrict__ Wconv,
                          const float* __restrict__ Wedge,
                          const float* __restrict__ Wg,
                          ushort_t* __restrict__ m1b) {
    int j = blockIdx.x;   // 0..130
    int o = threadIdx.x;  // 0..127
    const float* wrow = (j < 128) ? (Wconv + j * DINTER + 16)
                                  : (Wedge + (j - 128) * DINTER + 16);
    float acc = 0.f;
    for (int f = 0; f < 128; ++f)
        acc += wrow[f] * Wg[f * 128 + o];
    m1b[j * 128 + o] = (ushort_t)f2bf(acc);
}

// K2a: fused coarse histograms (LDS-aggregated).
// hA2: (src_slice, dst_node >> 9).  hC: src cluster >> 7 (dedupe).
__global__ void edge_hist2(const int* __restrict__ ei,
                           uint_t* __restrict__ bhA2, uint_t* __restrict__ bhC) {
    __shared__ uint_t hA[NBKT2], hC[NBKT];
    int tid = threadIdx.x;
    for (int i = tid; i < NBKT2; i += 256) hA[i] = 0;
    for (int i = tid; i < NBKT; i += 256) hC[i] = 0;
    __syncthreads();
    for (int e = blockIdx.x * 256 + tid; e < EE; e += 256 * 256) {
        uint_t u = (uint_t)ei[e];
        uint_t v = (uint_t)ei[EE + e];
        atomicAdd(&hA[(u / 12500u) * 196u + (v >> 9)], 1u);
        atomicAdd(&hC[u >> 9], 1u);
    }
    __syncthreads();
    for (int i = tid; i < NBKT2; i += 256) if (hA[i]) atomicAdd(&bhA2[i], hA[i]);
    for (int i = tid; i < NBKT; i += 256)  if (hC[i]) atomicAdd(&bhC[i], hC[i]);
}

// Single-block exclusive scan. out[0..n] (out[n]=total), optional copy out2[0..n-1].
__global__ void scan_small(const uint_t* __restrict__ in, uint_t* __restrict__ out,
                           uint_t* __restrict__ out2, int n) {
    __shared__ uint_t part[256];
    int tid = threadIdx.x;
    int per = (n + 255) >> 8;
    int lo = tid * per;
    int hi = lo + per; if (hi > n) hi = n;
    if (lo > n) lo = n;
    uint_t s = 0;
    for (int i = lo; i < hi; ++i) s += in[i];
    part[tid] = s;
    __syncthreads();
    for (int off = 1; off < 256; off <<= 1) {
        uint_t v = (tid >= off) ? part[tid - off] : 0u;
        __syncthreads();
        part[tid] += v;
        __syncthreads();
    }
    uint_t run = part[tid] - s;
    for (int i = lo; i < hi; ++i) {
        out[i] = run;
        if (out2) out2[i] = run;
        run += in[i];
    }
    if (tid == 255) out[n] = run;
}

#define TPB 4096
// K2b: bucket scatter for the reduce. Payload uint4 = {(cl<<17)|src, ea.x, ea.y, ea.z}
// so the reduce never gathers ei[] or ea[] (both read COALESCED here).
__global__ void bucket_place_A2(const int* __restrict__ ei, const float* __restrict__ ea,
                                uint_t* __restrict__ bcur, uint4* __restrict__ pk4) {
    __shared__ uint_t hist[NBKT2], gbase[NBKT2], cur[NBKT2];
    int tid = threadIdx.x;
    int t0 = blockIdx.x * TPB;
    int nt = EE - t0; if (nt > TPB) nt = TPB;
    for (int i = tid; i < NBKT2; i += 256) { hist[i] = 0; cur[i] = 0; }
    __syncthreads();
    for (int i = tid; i < nt; i += 256) {
        int e = t0 + i;
        uint_t u = (uint_t)ei[e];
        uint_t v = (uint_t)ei[EE + e];
        atomicAdd(&hist[(u / 12500u) * 196u + (v >> 9)], 1u);
    }
    __syncthreads();
    for (int b = tid; b < NBKT2; b += 256) {
        uint_t h = hist[b];
        if (h) gbase[b] = atomicAdd(&bcur[b], h);
    }
    __syncthreads();
    for (int i = tid; i < nt; i += 256) {
        int e = t0 + i;
        uint_t u = (uint_t)ei[e];
        uint_t v = (uint_t)ei[EE + e];
        uint_t b = (u / 12500u) * 196u + (v >> 9);
        uint_t r = gbase[b] + atomicAdd(&cur[b], 1u);
        uint4 p;
        p.x = (((v >> 2) & 127u) << 17) | u;
        p.y = __float_as_uint(ea[(size_t)e * 3 + 0]);
        p.z = __float_as_uint(ea[(size_t)e * 3 + 1]);
        p.w = __float_as_uint(ea[(size_t)e * 3 + 2]);
        pk4[r] = p;
    }
}

// K2b': dedupe-side bucket scatter; full key (u<<15)|v fits u32, bucket = pk>>22.
__global__ void bucket_place_C(const int* __restrict__ ei, uint_t* __restrict__ bcur,
                               uint_t* __restrict__ pkC) {
    __shared__ uint_t pk[TPB];
    __shared__ uint_t gpk[TPB];
    __shared__ uint_t hist[NBKT], lbase[NBKT], gbase[NBKT], cur[NBKT];
    __shared__ uint_t part[256];
    int tid = threadIdx.x;
    int t0 = blockIdx.x * TPB;
    int nt = EE - t0; if (nt > TPB) nt = TPB;
    for (int i = tid; i < NBKT; i += 256) { hist[i] = 0; cur[i] = 0; }
    __syncthreads();
    for (int i = tid; i < nt; i += 256) {
        int e = t0 + i;
        uint_t u = ((uint_t)ei[e]) >> 2;
        uint_t v = ((uint_t)ei[EE + e]) >> 2;
        uint_t w = (u << 15) | v;
        pk[i] = w;
        atomicAdd(&hist[w >> 22], 1u);
    }
    __syncthreads();
    uint_t h = (tid < NBKT) ? hist[tid] : 0u;
    if (tid < NBKT) gbase[tid] = atomicAdd(&bcur[tid], h);
    part[tid] = h;
    __syncthreads();
    for (int off = 1; off < 256; off <<= 1) {
        uint_t v = (tid >= off) ? part[tid - off] : 0u;
        __syncthreads();
        part[tid] += v;
        __syncthreads();
    }
    if (tid < NBKT) lbase[tid] = part[tid] - h;
    __syncthreads();
    for (int i = tid; i < nt; i += 256) {
        uint_t b = pk[i] >> 22;
        uint_t r = lbase[b] + atomicAdd(&cur[b], 1u);
        gpk[r] = pk[i];
    }
    __syncthreads();
    for (int r = tid; r < nt; r += 256) {
        uint_t b = gpk[r] >> 22;
        pkC[gbase[b] + ((uint_t)r - lbase[b])] = gpk[r];
    }
}

// K2c: in-LDS counting sort of each (slice, dst-coarse) bucket by cluster-local id,
// written back IN PLACE; emits offs2[kk] (kk = slice*25000 + cluster). Bucket size:
// Binomial(1.6M, 1/1568): mean 1020, sigma 32 -> 2048 = +32 sigma, overflow P ~ 0.
__global__ void bucket_sort_A2(const uint_t* __restrict__ bbA2, uint4* __restrict__ pk4,
                               uint_t* __restrict__ offs2) {
    __shared__ uint4 st[2048];                      // 32 KB payload staging
    __shared__ uint_t hist[128], base2[128], cur[128];
    __shared__ uint_t part[256];
    int tid = threadIdx.x, bk = blockIdx.x;
    uint_t s = bbA2[bk], epos = bbA2[bk + 1];
    int n = (int)(epos - s);
    if (n > 2048) n = 2048;   // statistically unreachable; guards LDS bounds
    if (tid < 128) { hist[tid] = 0; cur[tid] = 0; }
    for (int i = tid; i < n; i += 256) st[i] = pk4[s + i];
    __syncthreads();
    for (int i = tid; i < n; i += 256) atomicAdd(&hist[st[i].x >> 17], 1u);
    __syncthreads();
    uint_t h = (tid < 128) ? hist[tid] : 0u;
    part[tid] = h;
    __syncthreads();
    for (int off = 1; off < 256; off <<= 1) {
        uint_t v = (tid >= off) ? part[tid - off] : 0u;
        __syncthreads();
        part[tid] += v;
        __syncthreads();
    }
    int sl = bk / 196, q = bk - sl * 196;
    if (tid < 128) {
        base2[tid] = part[tid] - h;
        int c = q * 128 + tid;
        if (c < CC) offs2[sl * CC + c] = s + base2[tid];
    }
    if (bk == 0 && tid == 0) offs2[8 * CC] = EE;
    __syncthreads();
    for (int i = tid; i < n; i += 256) {
        uint4 p = st[i];
        uint_t d = p.x >> 17;
        uint_t r = base2[d] + atomicAdd(&cur[d], 1u);
        pk4[s + r] = p;
    }
}

// K3: per cluster: new_pos + new_batch straight to out (enc_emit reads out[O_POS]).
__global__ void cluster_pass(const float* __restrict__ pos, const int* __restrict__ batch,
                             float* __restrict__ out) {
    int c = blockIdx.x * 256 + threadIdx.x;
    if (c >= CC) return;
    float px = 0.f, py = 0.f, pz = 0.f;
    for (int j = 0; j < 4; ++j) {
        int n = c * 4 + j;
        px += pos[n * 3 + 0];
        py += pos[n * 3 + 1];
        pz += pos[n * 3 + 2];
    }
    px *= 0.25f; py *= 0.25f; pz *= 0.25f;
    out[O_POS + c * 3 + 0] = px;
    out[O_POS + c * 3 + 1] = py;
    out[O_POS + c * 3 + 2] = pz;
    int b = batch[c * 4];
    b = max(b, batch[c * 4 + 1]);
    b = max(b, batch[c * 4 + 2]);
    b = max(b, batch[c * 4 + 3]);
    out[O_BATCH + c] = (float)b;
}

// K2d: XCD-affine partial reduce, REGISTER accumulation (round-4 pattern; round-5's
// LDS-atomic accumulator was DS-pipe-bound at 2.3% VALUBusy). One wave per
// (slice s, cluster c) sorted segment (avg 8 edges). s = blockIdx&7 pins all gathers
// of x-slice s (3.2 MB) to one XCD's L2 (round-5 counters confirmed: FETCH 454->41 MB).
// src + ea come from the payload — no ei/ea gather. Empty segments write zero rows
// -> no memset and agg_merge stays exact.
__global__ void cluster_reduce3(const uint_t* __restrict__ offs2, const uint4* __restrict__ pk4,
                                const uint_t* __restrict__ xb, uint_t* __restrict__ paggw) {
    int tid = threadIdx.x;
    int lane = tid & 63;
    int s = blockIdx.x & 7;
    int c = (blockIdx.x >> 3) * 4 + (tid >> 6);     // 0..24999
    uint_t kk = (uint_t)s * CC + (uint_t)c;
    uint_t start = offs2[kk], end = offs2[kk + 1];
    float a0 = 0.f, a1 = 0.f, t0 = 0.f, t1 = 0.f, t2 = 0.f;
    for (uint_t base = start; base < end; base += 64u) {
        uint_t idx = base + (uint_t)lane;
        int nm = (int)min(64u, end - base);
        uint_t w = 0;
        if (idx < end) {
            uint4 p = pk4[idx];
            w = p.x;
            t0 += __uint_as_float(p.y);
            t1 += __uint_as_float(p.z);
            t2 += __uint_as_float(p.w);
        }
        for (int j = 0; j < nm; ++j) {
            uint_t wj = (uint_t)__shfl((int)w, j, 64);
            uint_t src = wj & 0x1FFFFu;
            uint_t xv = xb[(size_t)src * 64 + lane];
            a0 += bf2f((ushort_t)(xv & 0xffffu));
            a1 += bf2f((ushort_t)(xv >> 16));
        }
    }
    paggw[(size_t)kk * 66 + lane] = f2bf(a0) | (f2bf(a1) << 16);
    for (int off = 32; off; off >>= 1) {
        t0 += __shfl_down(t0, off, 64);
        t1 += __shfl_down(t1, off, 64);
        t2 += __shfl_down(t2, off, 64);
    }
    if (lane == 0) {
        paggw[(size_t)kk * 66 + 64] = f2bf(t0) | (f2bf(t1) << 16);
        paggw[(size_t)kk * 66 + 65] = f2bf(t2);   // slot 131 = 0
    }
}

// K2e: fold 8 slice-partials -> aggb (f32 sum of bf16 partials, bf16 out).
__global__ void agg_merge(const uint_t* __restrict__ paggw, uint_t* __restrict__ aggw) {
    int j = blockIdx.x * 256 + threadIdx.x;
    if (j >= 1650000) return;
    float lo = 0.f, hi = 0.f;
    #pragma unroll
    for (int s = 0; s < 8; ++s) {
        uint_t w = paggw[(size_t)s * 1650000u + (uint_t)j];
        lo += bf2f((ushort_t)(w & 0xffffu));
        hi += bf2f((ushort_t)(w >> 16));
    }
    aggw[j] = f2bf(lo) | (f2bf(hi) << 16);
}

// K4: x_new[c][o] = 0.25 * sum_{j<131} aggb[c][j] * M1[j][o].
#define GEMM_CPB 32   // clusters per block = 4 iterations of 8
__global__ void gemm_tiled(const ushort_t* __restrict__ aggb, const ushort_t* __restrict__ m1b,
                           float* __restrict__ out) {
    __shared__ ushort_t m1s[131 * 128];            // 33.5 KB bf16
    __shared__ __align__(16) float srowT[132][8];  // 4.2 KB, [j][cluster-in-group]
    int tid = threadIdx.x;
    {
        const uint_t* m1w = (const uint_t*)m1b;
        uint_t* m1sw = (uint_t*)m1s;
        for (int i = tid; i < 131 * 64; i += 256) m1sw[i] = m1w[i];
    }
    int o = tid & 127, half = tid >> 7;
    int c0b = blockIdx.x * GEMM_CPB;
    const uint_t* aggw = (const uint_t*)aggb;      // row = 66 u32 words
    for (int it = 0; it < GEMM_CPB / 8; ++it) {
        int c0 = c0b + it * 8;
        __syncthreads();   // previous-iteration readers done before overwrite
        for (int i = tid; i < 528; i += 256) {
            int cg = i / 66, rem = i - cg * 66;
            int c = c0 + cg;
            uint_t w = (c < CC) ? aggw[(size_t)c * 66 + rem] : 0u;
            srowT[rem * 2][cg]     = bf2f((ushort_t)(w & 0xffffu));
            srowT[rem * 2 + 1][cg] = bf2f((ushort_t)(w >> 16));
        }
        __syncthreads();   // also covers m1s staging on it==0
        float acc0 = 0.f, acc1 = 0.f, acc2 = 0.f, acc3 = 0.f;
        #pragma unroll 4
        for (int j = 0; j < 131; ++j) {
            float m = bf2f(m1s[j * 128 + o]);
            float4 s = *(const float4*)&srowT[j][half * 4];  // broadcast within wave
            acc0 += s.x * m;
            acc1 += s.y * m;
            acc2 += s.z * m;
            acc3 += s.w * m;
        }
        int cb = c0 + half * 4;
        if (cb + 0 < CC) out[O_XNEW + (size_t)(cb + 0) * 128 + o] = 0.25f * acc0;
        if (cb + 1 < CC) out[O_XNEW + (size_t)(cb + 1) * 128 + o] = 0.25f * acc1;
        if (cb + 2 < CC) out[O_XNEW + (size_t)(cb + 2) * 128 + o] = 0.25f * acc2;
        if (cb + 3 < CC) out[O_XNEW + (size_t)(cb + 3) * 128 + o] = 0.25f * acc3;
    }
}

// K6a: per-(bucket,sub) unique-(u,v) counts via 50 KB LDS bitmap (16 u-clusters x
// 25000 v bits). Grid = NBKT*8 — one block per sub-round.
__global__ void enc_count(const uint_t* __restrict__ bbC, const uint_t* __restrict__ pkC,
                          uint_t* __restrict__ bcnt) {
    __shared__ uint_t bmp[12500];
    __shared__ uint_t red[256];
    int tid = threadIdx.x;
    int bk = blockIdx.x >> 3;
    uint_t sub = (uint_t)(blockIdx.x & 7);
    uint_t s = bbC[bk], epos = bbC[bk + 1];
    int n = (int)(epos - s);
    for (int i = tid; i < 12500; i += 256) bmp[i] = 0;
    __syncthreads();
    for (int i = tid; i < n; i += 256) {
        uint_t w = pkC[s + i];
        if (((w >> 19) & 7u) == sub) {
            uint_t le = ((w >> 15) & 15u) * 25000u + (w & 32767u);
            atomicOr(&bmp[le >> 5], 1u << (le & 31u));
        }
    }
    __syncthreads();
    uint_t cnt = 0;
    for (int i = tid; i < 12500; i += 256) cnt += __popc(bmp[i]);
    red[tid] = cnt;
    __syncthreads();
    for (int off = 128; off; off >>= 1) {
        if (tid < off) red[tid] += red[tid + off];
        __syncthreads();
    }
    if (tid == 0) bcnt[blockIdx.x] = red[0];
}

// K6b: rebuild the (bucket,sub) LDS bitmap, rank via block scan, emit new edges +
// attrs in ascending enc order (bk asc, sub asc, word asc, bit asc == (u,v) lex asc).
__global__ void enc_emit(const uint_t* __restrict__ bbC, const uint_t* __restrict__ pkC,
                         const uint_t* __restrict__ ebase, float* __restrict__ out) {
    __shared__ uint_t bmp[12500];
    __shared__ uint_t sh[256];
    int tid = threadIdx.x;
    int bk = blockIdx.x >> 3;
    uint_t sub = (uint_t)(blockIdx.x & 7);
    uint_t s = bbC[bk], epos = bbC[bk + 1];
    int n = (int)(epos - s);
    const float* np = out + O_POS;   // new_pos [c*3], written by cluster_pass
    int lo = tid * 49, hi = lo + 49; if (hi > 12500) hi = 12500;
    for (int i = tid; i < 12500; i += 256) bmp[i] = 0;
    __syncthreads();
    for (int i = tid; i < n; i += 256) {
        uint_t w = pkC[s + i];
        if (((w >> 19) & 7u) == sub) {
            uint_t le = ((w >> 15) & 15u) * 25000u + (w & 32767u);
            atomicOr(&bmp[le >> 5], 1u << (le & 31u));
        }
    }
    __syncthreads();
    uint_t mine = 0;
    for (int i = lo; i < hi; ++i) mine += __popc(bmp[i]);
    sh[tid] = mine;
    __syncthreads();
    for (int off = 1; off < 256; off <<= 1) {
        uint_t v = (tid >= off) ? sh[tid - off] : 0u;
        __syncthreads();
        sh[tid] += v;
        __syncthreads();
    }
    uint_t rank = ebase[blockIdx.x] + sh[tid] - mine;
    uint_t ubase = (uint_t)bk * 128u + sub * 16u;
    for (int i = lo; i < hi; ++i) {
        uint_t bits = bmp[i];
        while (bits) {
            int b = __builtin_ctz(bits);
            bits &= bits - 1u;
            uint_t le = (uint_t)i * 32u + (uint_t)b;
            uint_t uo = le / 25000u;
            uint_t v = le - uo * 25000u;
            uint_t u = ubase + uo;
            out[O_EI + rank] = (float)u;
            out[O_EI + EE + rank] = (float)v;
            out[O_ATTR + (size_t)rank * 3 + 0] = np[v * 3 + 0] - np[u * 3 + 0];
            out[O_ATTR + (size_t)rank * 3 + 1] = np[v * 3 + 1] - np[u * 3 + 1];
            out[O_ATTR + (size_t)rank * 3 + 2] = np[v * 3 + 2] - np[u * 3 + 2];
            rank++;
        }
    }
}

extern "C" void kernel_launch(void* const* d_in, const int* in_sizes, int n_in,
                              void* d_out, int out_size, void* d_ws, size_t ws_size,
                              hipStream_t stream) {
    const float* x     = (const float*)d_in[0];
    const float* pos   = (const float*)d_in[1];
    const int*   ei    = (const int*)d_in[2];
    const float* ea    = (const float*)d_in[3];
    const int*   batch = (const int*)d_in[4];
    const float* Wconv = (const float*)d_in[5];
    const float* Wedge = (const float*)d_in[6];
    // d_in[7] = D_bloom: dead (bloom_pos never reaches an output)
    const float* Wg    = (const float*)d_in[8];
    // d_in[9] = W_gattr: contribution cancels exactly within each cluster

    float*  out = (float*)d_out;
    uint_t* ws  = (uint_t*)d_ws;

    if (ws_size < (size_t)WS_WORDS * 4) return;

    ushort_t* m1b    = (ushort_t*)(ws + W_M1B);
    ushort_t* aggb   = (ushort_t*)(ws + W_AGGB);
    uint_t*   paggw  = ws + W_PAGG;
    uint4*    pk4    = (uint4*)(ws + W_PKA4);
    uint_t*   pkC    = ws + W_PKC;
    uint_t*   offs2  = ws + W_OFFS2;
    uint_t*   bhA2   = ws + W_BHA2;
    uint_t*   bhC    = ws + W_BHC;
    uint_t*   bbA2   = ws + W_BBA2;
    uint_t*   bcurA2 = ws + W_BCURA2;
    uint_t*   bbC    = ws + W_BBC;
    uint_t*   bcurC  = ws + W_BCURC;
    uint_t*   bcntC  = ws + W_BCNTC;
    uint_t*   ebase  = ws + W_EBASE;
    uint_t*   xb     = (uint_t*)(out + O_EI);   // 6.4M-word bf16-x staging in out region

    hipMemsetAsync(bhA2, 0, (size_t)(NBKT2 + NBKT) * 4, stream);   // bhA2 + bhC contiguous

    xpack<<<dim3(12500), dim3(256), 0, stream>>>((const float4*)x, (uint2*)xb);
    build_m1f<<<dim3(131), dim3(128), 0, stream>>>(Wconv, Wedge, Wg, m1b);
    edge_hist2<<<dim3(256), dim3(256), 0, stream>>>(ei, bhA2, bhC);
    scan_small<<<dim3(1), dim3(256), 0, stream>>>(bhA2, bbA2, bcurA2, NBKT2);
    scan_small<<<dim3(1), dim3(256), 0, stream>>>(bhC, bbC, bcurC, NBKT);
    bucket_place_A2<<<dim3((EE + TPB - 1) / TPB), dim3(256), 0, stream>>>(ei, ea, bcurA2, pk4);
    bucket_place_C<<<dim3((EE + TPB - 1) / TPB), dim3(256), 0, stream>>>(ei, bcurC, pkC);
    bucket_sort_A2<<<dim3(NBKT2), dim3(256), 0, stream>>>(bbA2, pk4, offs2);
    cluster_pass<<<dim3(98), dim3(256), 0, stream>>>(pos, batch, out);
    cluster_reduce3<<<dim3(50000), dim3(256), 0, stream>>>(offs2, pk4, xb, paggw);
    agg_merge<<<dim3(6446), dim3(256), 0, stream>>>(paggw, (uint_t*)aggb);
    gemm_tiled<<<dim3((CC + GEMM_CPB - 1) / GEMM_CPB), dim3(256), 0, stream>>>(aggb, m1b, out);
    // x_bf16 staging no longer needed: zero the EI/ATTR region (incl. padding tail)
    hipMemsetAsync((char*)d_out + (size_t)O_EI * 4, 0, (size_t)(3200000 + 4800000) * 4, stream);
    enc_count<<<dim3(NBKT * 8), dim3(256), 0, stream>>>(bbC, pkC, bcntC);
    scan_small<<<dim3(1), dim3(256), 0, stream>>>(bcntC, ebase, (uint_t*)0, NBKT * 8);
    enc_emit<<<dim3(NBKT * 8), dim3(256), 0, stream>>>(bbC, pkC, ebase, out);
}

// Round 7
// 489.005 us; speedup vs baseline: 3.4090x; 1.2491x over previous
//
#include <hip/hip_runtime.h>
#include <hip/hip_bf16.h>
#include <stdint.h>

typedef unsigned int uint_t;
typedef unsigned short ushort_t;

#define NN 100000
#define EE 1600000
#define CC 25000
#define DINTER 144
#define NBKT 196          // C-side coarse buckets: src cluster >> 7
#define NBKT2 1568        // A-side buckets: (src_node/12500)*196 + (dst_node>>9)
#define NSEG 6272         // dedupe segments: 196 buckets * 32 subs (4 u-clusters each)
#define KCAP 1024         // keys per segment cap (mean 256, sigma 16 -> +48 sigma)

// ---- ws layout in 32-bit words (total 92.27 MB, proven last round) ----
#define W_M1B      0u         // u16 [131*128] bf16 m1 = 8384 words
#define W_AGGB     8384u      // bf16[25000*132] = 1,650,000 words
#define W_PAGG     1658384u   // bf16[8][25000*132] = 13,200,000 words (kbuf reuse after agg_merge)
#define W_PKA4     14858384u  // uint4[1,600,000] = 6,400,000 words (csub/bcnt/ebase reuse after reduce)
#define W_PKC      21258384u  // u32 [1600000]
#define W_OFFS2    22858384u  // u32 [200001]  per-(slice,cluster) segment offsets
#define W_BHA2     23058385u  // u32 [1568]
#define W_BHC      23059953u  // u32 [196]   (adjacent to BHA2: one memset of 1764)
#define W_BBA2     23060149u  // u32 [1569]
#define W_BCURA2   23061718u  // u32 [1568]
#define W_BBC      23063286u  // u32 [197]
#define W_BCURC    23063483u  // u32 [196]
#define WS_WORDS   23066816u

// ---- out layout in FLOAT32 elements (total 11,300,000) ----
#define O_XNEW  0u
#define O_POS   3200000u
#define O_EI    3275000u
#define O_ATTR  6475000u
#define O_BATCH 11275000u
// x_bf16 staging: first 6.4M words of the O_EI region (re-zeroed before enc_count/emit)
// new_pos f32[25000*3] lives at out[O_POS] and is read back by enc_emit.

static __device__ __forceinline__ uint_t f2bf(float f) {
    union { float f; uint_t i; } v; v.f = f;
    uint_t x = v.i;
    return (x + 0x7fffu + ((x >> 16) & 1u)) >> 16;  // RNE
}
static __device__ __forceinline__ float bf2f(ushort_t u) {
    union { uint_t i; float f; } v; v.i = ((uint_t)u) << 16; return v.f;
}

// K0: pack x (f32) -> bf16x2 words into the output-staging region.
__global__ void xpack(const float4* __restrict__ x4, uint2* __restrict__ xb2) {
    int i = blockIdx.x * 256 + threadIdx.x;
    if (i >= NN * 32) return;            // 12.8M floats / 4
    float4 v = x4[i];
    uint2 r;
    r.x = f2bf(v.x) | (f2bf(v.y) << 16);
    r.y = f2bf(v.z) | (f2bf(v.w) << 16);
    xb2[i] = r;
}

// K1: M1[j][o] = sum_f Wrow_j[f] * Wg[f][o], emitted directly as bf16.
__global__ void build_m1f(const float* __restrict__ Wconv,
                          const float* __restrict__ Wedge,
                          const float* __restrict__ Wg,
                          ushort_t* __restrict__ m1b) {
    int j = blockIdx.x;   // 0..130
    int o = threadIdx.x;  // 0..127
    const float* wrow = (j < 128) ? (Wconv + j * DINTER + 16)
                                  : (Wedge + (j - 128) * DINTER + 16);
    float acc = 0.f;
    for (int f = 0; f < 128; ++f)
        acc += wrow[f] * Wg[f * 128 + o];
    m1b[j * 128 + o] = (ushort_t)f2bf(acc);
}

// K2a: fused coarse histograms (LDS-aggregated).
// hA2: (src_slice, dst_node >> 9).  hC: src cluster >> 7 (dedupe).
__global__ void edge_hist2(const int* __restrict__ ei,
                           uint_t* __restrict__ bhA2, uint_t* __restrict__ bhC) {
    __shared__ uint_t hA[NBKT2], hC[NBKT];
    int tid = threadIdx.x;
    for (int i = tid; i < NBKT2; i += 256) hA[i] = 0;
    for (int i = tid; i < NBKT; i += 256) hC[i] = 0;
    __syncthreads();
    for (int e = blockIdx.x * 256 + tid; e < EE; e += 256 * 256) {
        uint_t u = (uint_t)ei[e];
        uint_t v = (uint_t)ei[EE + e];
        atomicAdd(&hA[(u / 12500u) * 196u + (v >> 9)], 1u);
        atomicAdd(&hC[u >> 9], 1u);
    }
    __syncthreads();
    for (int i = tid; i < NBKT2; i += 256) if (hA[i]) atomicAdd(&bhA2[i], hA[i]);
    for (int i = tid; i < NBKT; i += 256)  if (hC[i]) atomicAdd(&bhC[i], hC[i]);
}

// Single-block exclusive scan. out[0..n] (out[n]=total), optional copy out2[0..n-1].
__global__ void scan_small(const uint_t* __restrict__ in, uint_t* __restrict__ out,
                           uint_t* __restrict__ out2, int n) {
    __shared__ uint_t part[256];
    int tid = threadIdx.x;
    int per = (n + 255) >> 8;
    int lo = tid * per;
    int hi = lo + per; if (hi > n) hi = n;
    if (lo > n) lo = n;
    uint_t s = 0;
    for (int i = lo; i < hi; ++i) s += in[i];
    part[tid] = s;
    __syncthreads();
    for (int off = 1; off < 256; off <<= 1) {
        uint_t v = (tid >= off) ? part[tid - off] : 0u;
        __syncthreads();
        part[tid] += v;
        __syncthreads();
    }
    uint_t run = part[tid] - s;
    for (int i = lo; i < hi; ++i) {
        out[i] = run;
        if (out2) out2[i] = run;
        run += in[i];
    }
    if (tid == 255) out[n] = run;
}

#define TPB 4096
// K2b: bucket scatter for the reduce. Payload uint4 = {(cl<<17)|src, ea.x, ea.y, ea.z}
// so the reduce never gathers ei[] or ea[] (both read COALESCED here).
__global__ void bucket_place_A2(const int* __restrict__ ei, const float* __restrict__ ea,
                                uint_t* __restrict__ bcur, uint4* __restrict__ pk4) {
    __shared__ uint_t hist[NBKT2], gbase[NBKT2], cur[NBKT2];
    int tid = threadIdx.x;
    int t0 = blockIdx.x * TPB;
    int nt = EE - t0; if (nt > TPB) nt = TPB;
    for (int i = tid; i < NBKT2; i += 256) { hist[i] = 0; cur[i] = 0; }
    __syncthreads();
    for (int i = tid; i < nt; i += 256) {
        int e = t0 + i;
        uint_t u = (uint_t)ei[e];
        uint_t v = (uint_t)ei[EE + e];
        atomicAdd(&hist[(u / 12500u) * 196u + (v >> 9)], 1u);
    }
    __syncthreads();
    for (int b = tid; b < NBKT2; b += 256) {
        uint_t h = hist[b];
        if (h) gbase[b] = atomicAdd(&bcur[b], h);
    }
    __syncthreads();
    for (int i = tid; i < nt; i += 256) {
        int e = t0 + i;
        uint_t u = (uint_t)ei[e];
        uint_t v = (uint_t)ei[EE + e];
        uint_t b = (u / 12500u) * 196u + (v >> 9);
        uint_t r = gbase[b] + atomicAdd(&cur[b], 1u);
        uint4 p;
        p.x = (((v >> 2) & 127u) << 17) | u;
        p.y = __float_as_uint(ea[(size_t)e * 3 + 0]);
        p.z = __float_as_uint(ea[(size_t)e * 3 + 1]);
        p.w = __float_as_uint(ea[(size_t)e * 3 + 2]);
        pk4[r] = p;
    }
}

// K2b': dedupe-side bucket scatter; full key (u<<15)|v fits u32, bucket = pk>>22.
__global__ void bucket_place_C(const int* __restrict__ ei, uint_t* __restrict__ bcur,
                               uint_t* __restrict__ pkC) {
    __shared__ uint_t pk[TPB];
    __shared__ uint_t gpk[TPB];
    __shared__ uint_t hist[NBKT], lbase[NBKT], gbase[NBKT], cur[NBKT];
    __shared__ uint_t part[256];
    int tid = threadIdx.x;
    int t0 = blockIdx.x * TPB;
    int nt = EE - t0; if (nt > TPB) nt = TPB;
    for (int i = tid; i < NBKT; i += 256) { hist[i] = 0; cur[i] = 0; }
    __syncthreads();
    for (int i = tid; i < nt; i += 256) {
        int e = t0 + i;
        uint_t u = ((uint_t)ei[e]) >> 2;
        uint_t v = ((uint_t)ei[EE + e]) >> 2;
        uint_t w = (u << 15) | v;
        pk[i] = w;
        atomicAdd(&hist[w >> 22], 1u);
    }
    __syncthreads();
    uint_t h = (tid < NBKT) ? hist[tid] : 0u;
    if (tid < NBKT) gbase[tid] = atomicAdd(&bcur[tid], h);
    part[tid] = h;
    __syncthreads();
    for (int off = 1; off < 256; off <<= 1) {
        uint_t v = (tid >= off) ? part[tid - off] : 0u;
        __syncthreads();
        part[tid] += v;
        __syncthreads();
    }
    if (tid < NBKT) lbase[tid] = part[tid] - h;
    __syncthreads();
    for (int i = tid; i < nt; i += 256) {
        uint_t b = pk[i] >> 22;
        uint_t r = lbase[b] + atomicAdd(&cur[b], 1u);
        gpk[r] = pk[i];
    }
    __syncthreads();
    for (int r = tid; r < nt; r += 256) {
        uint_t b = gpk[r] >> 22;
        pkC[gbase[b] + ((uint_t)r - lbase[b])] = gpk[r];
    }
}

// K2c: in-LDS counting sort of each (slice, dst-coarse) bucket by cluster-local id,
// written back IN PLACE; emits offs2[kk] (kk = slice*25000 + cluster). Bucket size:
// Binomial(1.6M, 1/1568): mean 1020, sigma 32 -> 2048 = +32 sigma, overflow P ~ 0.
__global__ void bucket_sort_A2(const uint_t* __restrict__ bbA2, uint4* __restrict__ pk4,
                               uint_t* __restrict__ offs2) {
    __shared__ uint4 st[2048];                      // 32 KB payload staging
    __shared__ uint_t hist[128], base2[128], cur[128];
    __shared__ uint_t part[256];
    int tid = threadIdx.x, bk = blockIdx.x;
    uint_t s = bbA2[bk], epos = bbA2[bk + 1];
    int n = (int)(epos - s);
    if (n > 2048) n = 2048;   // statistically unreachable; guards LDS bounds
    if (tid < 128) { hist[tid] = 0; cur[tid] = 0; }
    for (int i = tid; i < n; i += 256) st[i] = pk4[s + i];
    __syncthreads();
    for (int i = tid; i < n; i += 256) atomicAdd(&hist[st[i].x >> 17], 1u);
    __syncthreads();
    uint_t h = (tid < 128) ? hist[tid] : 0u;
    part[tid] = h;
    __syncthreads();
    for (int off = 1; off < 256; off <<= 1) {
        uint_t v = (tid >= off) ? part[tid - off] : 0u;
        __syncthreads();
        part[tid] += v;
        __syncthreads();
    }
    int sl = bk / 196, q = bk - sl * 196;
    if (tid < 128) {
        base2[tid] = part[tid] - h;
        int c = q * 128 + tid;
        if (c < CC) offs2[sl * CC + c] = s + base2[tid];
    }
    if (bk == 0 && tid == 0) offs2[8 * CC] = EE;
    __syncthreads();
    for (int i = tid; i < n; i += 256) {
        uint4 p = st[i];
        uint_t d = p.x >> 17;
        uint_t r = base2[d] + atomicAdd(&cur[d], 1u);
        pk4[s + r] = p;
    }
}

// K2c': counting-sort each C-bucket by 5-bit sub key ((u>>2)&31), in place, so the
// dedupe kernels read ONLY their own ~256-entry segment (was: whole 8200-entry
// bucket re-read+filtered by 8 blocks = 8x redundant scan, the enc_* bottleneck).
__global__ void bucket_sort_C(const uint_t* __restrict__ bbC, uint_t* __restrict__ pkC,
                              uint_t* __restrict__ csub) {
    __shared__ uint_t st[8960];                     // 35.8 KB (bucket mean 8192, +8.5 sigma)
    __shared__ uint_t hist[32], base2[32], cur[32];
    __shared__ uint_t part[256];
    int tid = threadIdx.x, bk = blockIdx.x;
    uint_t s = bbC[bk], epos = bbC[bk + 1];
    int n = (int)(epos - s);
    if (n > 8960) n = 8960;
    if (tid < 32) { hist[tid] = 0; cur[tid] = 0; }
    for (int i = tid; i < n; i += 256) st[i] = pkC[s + i];
    __syncthreads();
    for (int i = tid; i < n; i += 256) atomicAdd(&hist[(st[i] >> 17) & 31u], 1u);
    __syncthreads();
    uint_t h = (tid < 32) ? hist[tid] : 0u;
    part[tid] = h;
    __syncthreads();
    for (int off = 1; off < 256; off <<= 1) {
        uint_t v = (tid >= off) ? part[tid - off] : 0u;
        __syncthreads();
        part[tid] += v;
        __syncthreads();
    }
    if (tid < 32) {
        base2[tid] = part[tid] - h;
        csub[bk * 32 + tid] = s + base2[tid];
    }
    if (bk == 0 && tid == 0) csub[NSEG] = EE;
    __syncthreads();
    for (int i = tid; i < n; i += 256) {
        uint_t w = st[i];
        uint_t d = (w >> 17) & 31u;
        uint_t r = base2[d] + atomicAdd(&cur[d], 1u);
        pkC[s + r] = w;
    }
}

// K3: per cluster: new_pos + new_batch straight to out (enc_emit reads out[O_POS]).
__global__ void cluster_pass(const float* __restrict__ pos, const int* __restrict__ batch,
                             float* __restrict__ out) {
    int c = blockIdx.x * 256 + threadIdx.x;
    if (c >= CC) return;
    float px = 0.f, py = 0.f, pz = 0.f;
    for (int j = 0; j < 4; ++j) {
        int n = c * 4 + j;
        px += pos[n * 3 + 0];
        py += pos[n * 3 + 1];
        pz += pos[n * 3 + 2];
    }
    px *= 0.25f; py *= 0.25f; pz *= 0.25f;
    out[O_POS + c * 3 + 0] = px;
    out[O_POS + c * 3 + 1] = py;
    out[O_POS + c * 3 + 2] = pz;
    int b = batch[c * 4];
    b = max(b, batch[c * 4 + 1]);
    b = max(b, batch[c * 4 + 2]);
    b = max(b, batch[c * 4 + 3]);
    out[O_BATCH + c] = (float)b;
}

// K2d: XCD-affine partial reduce, REGISTER accumulation. One wave per (slice s,
// cluster c) sorted segment. s = blockIdx&7 pins all gathers of x-slice s (3.2 MB)
// to one XCD's L2 (round-5 counters confirmed: FETCH 454->41 MB).
__global__ void cluster_reduce3(const uint_t* __restrict__ offs2, const uint4* __restrict__ pk4,
                                const uint_t* __restrict__ xb, uint_t* __restrict__ paggw) {
    int tid = threadIdx.x;
    int lane = tid & 63;
    int s = blockIdx.x & 7;
    int c = (blockIdx.x >> 3) * 4 + (tid >> 6);     // 0..24999
    uint_t kk = (uint_t)s * CC + (uint_t)c;
    uint_t start = offs2[kk], end = offs2[kk + 1];
    float a0 = 0.f, a1 = 0.f, t0 = 0.f, t1 = 0.f, t2 = 0.f;
    for (uint_t base = start; base < end; base += 64u) {
        uint_t idx = base + (uint_t)lane;
        int nm = (int)min(64u, end - base);
        uint_t w = 0;
        if (idx < end) {
            uint4 p = pk4[idx];
            w = p.x;
            t0 += __uint_as_float(p.y);
            t1 += __uint_as_float(p.z);
            t2 += __uint_as_float(p.w);
        }
        for (int j = 0; j < nm; ++j) {
            uint_t wj = (uint_t)__shfl((int)w, j, 64);
            uint_t src = wj & 0x1FFFFu;
            uint_t xv = xb[(size_t)src * 64 + lane];
            a0 += bf2f((ushort_t)(xv & 0xffffu));
            a1 += bf2f((ushort_t)(xv >> 16));
        }
    }
    paggw[(size_t)kk * 66 + lane] = f2bf(a0) | (f2bf(a1) << 16);
    for (int off = 32; off; off >>= 1) {
        t0 += __shfl_down(t0, off, 64);
        t1 += __shfl_down(t1, off, 64);
        t2 += __shfl_down(t2, off, 64);
    }
    if (lane == 0) {
        paggw[(size_t)kk * 66 + 64] = f2bf(t0) | (f2bf(t1) << 16);
        paggw[(size_t)kk * 66 + 65] = f2bf(t2);   // slot 131 = 0
    }
}

// K2e: fold 8 slice-partials -> aggb (f32 sum of bf16 partials, bf16 out).
__global__ void agg_merge(const uint_t* __restrict__ paggw, uint_t* __restrict__ aggw) {
    int j = blockIdx.x * 256 + threadIdx.x;
    if (j >= 1650000) return;
    float lo = 0.f, hi = 0.f;
    #pragma unroll
    for (int s = 0; s < 8; ++s) {
        uint_t w = paggw[(size_t)s * 1650000u + (uint_t)j];
        lo += bf2f((ushort_t)(w & 0xffffu));
        hi += bf2f((ushort_t)(w >> 16));
    }
    aggw[j] = f2bf(lo) | (f2bf(hi) << 16);
}

// K4: x_new[c][o] = 0.25 * sum_{j<131} aggb[c][j] * M1[j][o].
#define GEMM_CPB 32   // clusters per block = 4 iterations of 8
__global__ void gemm_tiled(const ushort_t* __restrict__ aggb, const ushort_t* __restrict__ m1b,
                           float* __restrict__ out) {
    __shared__ ushort_t m1s[131 * 128];            // 33.5 KB bf16
    __shared__ __align__(16) float srowT[132][8];  // 4.2 KB, [j][cluster-in-group]
    int tid = threadIdx.x;
    {
        const uint_t* m1w = (const uint_t*)m1b;
        uint_t* m1sw = (uint_t*)m1s;
        for (int i = tid; i < 131 * 64; i += 256) m1sw[i] = m1w[i];
    }
    int o = tid & 127, half = tid >> 7;
    int c0b = blockIdx.x * GEMM_CPB;
    const uint_t* aggw = (const uint_t*)aggb;      // row = 66 u32 words
    for (int it = 0; it < GEMM_CPB / 8; ++it) {
        int c0 = c0b + it * 8;
        __syncthreads();   // previous-iteration readers done before overwrite
        for (int i = tid; i < 528; i += 256) {
            int cg = i / 66, rem = i - cg * 66;
            int c = c0 + cg;
            uint_t w = (c < CC) ? aggw[(size_t)c * 66 + rem] : 0u;
            srowT[rem * 2][cg]     = bf2f((ushort_t)(w & 0xffffu));
            srowT[rem * 2 + 1][cg] = bf2f((ushort_t)(w >> 16));
        }
        __syncthreads();   // also covers m1s staging on it==0
        float acc0 = 0.f, acc1 = 0.f, acc2 = 0.f, acc3 = 0.f;
        #pragma unroll 4
        for (int j = 0; j < 131; ++j) {
            float m = bf2f(m1s[j * 128 + o]);
            float4 s = *(const float4*)&srowT[j][half * 4];  // broadcast within wave
            acc0 += s.x * m;
            acc1 += s.y * m;
            acc2 += s.z * m;
            acc3 += s.w * m;
        }
        int cb = c0 + half * 4;
        if (cb + 0 < CC) out[O_XNEW + (size_t)(cb + 0) * 128 + o] = 0.25f * acc0;
        if (cb + 1 < CC) out[O_XNEW + (size_t)(cb + 1) * 128 + o] = 0.25f * acc1;
        if (cb + 2 < CC) out[O_XNEW + (size_t)(cb + 2) * 128 + o] = 0.25f * acc2;
        if (cb + 3 < CC) out[O_XNEW + (size_t)(cb + 3) * 128 + o] = 0.25f * acc3;
    }
}

// K6a: per-segment dedupe: read OWN ~256-entry segment, 12.5 KB LDS bitmap
// (4 u-clusters x 25000 v bits), block scan, emit deduped keys (le, rank-dense)
// to kbuf[bid*KCAP] + count. Bitmap built ONCE (emit kernel reads keys, not pkC).
__global__ void enc_count(const uint_t* __restrict__ csub, const uint_t* __restrict__ pkC,
                          uint_t* __restrict__ bcnt, uint_t* __restrict__ kbuf) {
    __shared__ uint_t bmp[3125];
    __shared__ uint_t sh[256];
    int tid = threadIdx.x, bid = blockIdx.x;
    uint_t s = csub[bid], epos = csub[bid + 1];
    int n = (int)(epos - s);
    for (int i = tid; i < 3125; i += 256) bmp[i] = 0;
    __syncthreads();
    for (int i = tid; i < n; i += 256) {
        uint_t w = pkC[s + i];
        uint_t le = ((w >> 15) & 3u) * 25000u + (w & 32767u);
        atomicOr(&bmp[le >> 5], 1u << (le & 31u));
    }
    __syncthreads();
    int lo = tid * 13, hi = lo + 13;
    if (lo > 3125) lo = 3125;
    if (hi > 3125) hi = 3125;
    uint_t mine = 0;
    for (int i = lo; i < hi; ++i) mine += __popc(bmp[i]);
    sh[tid] = mine;
    __syncthreads();
    for (int off = 1; off < 256; off <<= 1) {
        uint_t v = (tid >= off) ? sh[tid - off] : 0u;
        __syncthreads();
        sh[tid] += v;
        __syncthreads();
    }
    uint_t r = sh[tid] - mine;
    uint_t kb = (uint_t)bid * KCAP;
    for (int i = lo; i < hi; ++i) {
        uint_t bits = bmp[i];
        while (bits) {
            int b = __builtin_ctz(bits);
            bits &= bits - 1u;
            if (r < KCAP) kbuf[kb + r] = (uint_t)i * 32u + (uint_t)b;
            r++;
        }
    }
    if (tid == 255) bcnt[bid] = min(sh[255], (uint_t)KCAP);
}

// K6b: decode dense keys, write u/v COALESCED + attrs (np gathers are L2-resident).
// Global order: bid asc (= u-group asc), key asc within (= (u&3, v) asc) ->
// ascending enc, identical to jnp.unique output order.
__global__ void enc_emit(const uint_t* __restrict__ ebase, const uint_t* __restrict__ kbuf,
                         float* __restrict__ out) {
    int tid = threadIdx.x, bid = blockIdx.x;
    uint_t g0 = ebase[bid], g1 = ebase[bid + 1];
    int cnt = (int)(g1 - g0);
    const float* np = out + O_POS;
    uint_t ubase = ((uint_t)(bid >> 5)) * 128u + ((uint_t)(bid & 31)) * 4u;
    uint_t kb = (uint_t)bid * KCAP;
    for (int r = tid; r < cnt; r += 256) {
        uint_t le = kbuf[kb + r];
        uint_t uo = le / 25000u;
        uint_t v = le - uo * 25000u;
        uint_t u = ubase + uo;
        uint_t rank = g0 + (uint_t)r;
        out[O_EI + rank] = (float)u;
        out[O_EI + EE + rank] = (float)v;
        out[O_ATTR + (size_t)rank * 3 + 0] = np[v * 3 + 0] - np[u * 3 + 0];
        out[O_ATTR + (size_t)rank * 3 + 1] = np[v * 3 + 1] - np[u * 3 + 1];
        out[O_ATTR + (size_t)rank * 3 + 2] = np[v * 3 + 2] - np[u * 3 + 2];
    }
}

extern "C" void kernel_launch(void* const* d_in, const int* in_sizes, int n_in,
                              void* d_out, int out_size, void* d_ws, size_t ws_size,
                              hipStream_t stream) {
    const float* x     = (const float*)d_in[0];
    const float* pos   = (const float*)d_in[1];
    const int*   ei    = (const int*)d_in[2];
    const float* ea    = (const float*)d_in[3];
    const int*   batch = (const int*)d_in[4];
    const float* Wconv = (const float*)d_in[5];
    const float* Wedge = (const float*)d_in[6];
    // d_in[7] = D_bloom: dead (bloom_pos never reaches an output)
    const float* Wg    = (const float*)d_in[8];
    // d_in[9] = W_gattr: contribution cancels exactly within each cluster

    float*  out = (float*)d_out;
    uint_t* ws  = (uint_t*)d_ws;

    if (ws_size < (size_t)WS_WORDS * 4) return;

    ushort_t* m1b    = (ushort_t*)(ws + W_M1B);
    ushort_t* aggb   = (ushort_t*)(ws + W_AGGB);
    uint_t*   paggw  = ws + W_PAGG;
    uint4*    pk4    = (uint4*)(ws + W_PKA4);
    uint_t*   pkC    = ws + W_PKC;
    uint_t*   offs2  = ws + W_OFFS2;
    uint_t*   bhA2   = ws + W_BHA2;
    uint_t*   bhC    = ws + W_BHC;
    uint_t*   bbA2   = ws + W_BBA2;
    uint_t*   bcurA2 = ws + W_BCURA2;
    uint_t*   bbC    = ws + W_BBC;
    uint_t*   bcurC  = ws + W_BCURC;
    uint_t*   xb     = (uint_t*)(out + O_EI);   // 6.4M-word bf16-x staging in out region
    // dead-region reuse (valid after cluster_reduce3 / agg_merge):
    uint_t*   csub   = ws + W_PKA4;             // u32 [NSEG+1]
    uint_t*   bcnt2  = ws + W_PKA4 + 8192u;     // u32 [NSEG]
    uint_t*   ebase2 = ws + W_PKA4 + 16384u;    // u32 [NSEG+1]
    uint_t*   kbuf   = ws + W_PAGG;             // u32 [NSEG*KCAP] = 6.42M <= 13.2M

    hipMemsetAsync(bhA2, 0, (size_t)(NBKT2 + NBKT) * 4, stream);   // bhA2 + bhC contiguous

    xpack<<<dim3(12500), dim3(256), 0, stream>>>((const float4*)x, (uint2*)xb);
    build_m1f<<<dim3(131), dim3(128), 0, stream>>>(Wconv, Wedge, Wg, m1b);
    edge_hist2<<<dim3(256), dim3(256), 0, stream>>>(ei, bhA2, bhC);
    scan_small<<<dim3(1), dim3(256), 0, stream>>>(bhA2, bbA2, bcurA2, NBKT2);
    scan_small<<<dim3(1), dim3(256), 0, stream>>>(bhC, bbC, bcurC, NBKT);
    bucket_place_A2<<<dim3((EE + TPB - 1) / TPB), dim3(256), 0, stream>>>(ei, ea, bcurA2, pk4);
    bucket_place_C<<<dim3((EE + TPB - 1) / TPB), dim3(256), 0, stream>>>(ei, bcurC, pkC);
    bucket_sort_A2<<<dim3(NBKT2), dim3(256), 0, stream>>>(bbA2, pk4, offs2);
    cluster_pass<<<dim3(98), dim3(256), 0, stream>>>(pos, batch, out);
    cluster_reduce3<<<dim3(50000), dim3(256), 0, stream>>>(offs2, pk4, xb, paggw);
    agg_merge<<<dim3(6446), dim3(256), 0, stream>>>(paggw, (uint_t*)aggb);
    gemm_tiled<<<dim3((CC + GEMM_CPB - 1) / GEMM_CPB), dim3(256), 0, stream>>>(aggb, m1b, out);
    // x_bf16 staging no longer needed: zero the EI/ATTR region (incl. padding tail)
    hipMemsetAsync((char*)d_out + (size_t)O_EI * 4, 0, (size_t)(3200000 + 4800000) * 4, stream);
    bucket_sort_C<<<dim3(NBKT), dim3(256), 0, stream>>>(bbC, pkC, csub);
    enc_count<<<dim3(NSEG), dim3(256), 0, stream>>>(csub, pkC, bcnt2, kbuf);
    scan_small<<<dim3(1), dim3(256), 0, stream>>>(bcnt2, ebase2, (uint_t*)0, NSEG);
    enc_emit<<<dim3(NSEG), dim3(256), 0, stream>>>(ebase2, kbuf, out);
}

// Round 8
// 481.327 us; speedup vs baseline: 3.4634x; 1.0160x over previous
//
#include <hip/hip_runtime.h>
#include <hip/hip_bf16.h>
#include <stdint.h>

typedef unsigned int uint_t;
typedef unsigned short ushort_t;

#define NN 100000
#define EE 1600000
#define CC 25000
#define DINTER 144
#define NBKT 196          // C-side coarse buckets: src cluster >> 7
#define NBKT2 1568        // A-side buckets: (src_node/12500)*196 + (dst_node>>9)
#define NSEG 6272         // dedupe segments: 196 buckets * 32 subs (4 u-clusters each)
#define KCAP 1024         // keys per segment cap (mean 256, sigma 16 -> +48 sigma)

// ---- ws layout in 32-bit words (total 92.27 MB, proven) ----
#define W_M1B      0u         // u16 [131*128] bf16 m1 = 8384 words
#define W_AGGB     8384u      // bf16[25000*132] = 1,650,000 words (pkW alias pre-agg_merge)
#define W_PAGG     1658384u   // bf16[8][25000*132] = 13,200,000 words (kbuf reuse after agg_merge)
#define W_PKA4     14858384u  // uint4[1,600,000] = 6,400,000 words (csub/bcnt/ebase reuse after sort)
#define W_PKC      21258384u  // u32 [1600000]
#define W_OFFS2    22858384u  // u32 [200001]  per-(slice,cluster) segment offsets
#define W_BHA2     23058385u  // u32 [1568]
#define W_BHC      23059953u  // u32 [196]   (adjacent to BHA2: one memset of 1764)
#define W_BBA2     23060149u  // u32 [1569]
#define W_BCURA2   23061718u  // u32 [1568]
#define W_BBC      23063286u  // u32 [197]
#define W_BCURC    23063483u  // u32 [196]
#define WS_WORDS   23066816u

// ---- out layout in FLOAT32 elements (total 11,300,000) ----
#define O_XNEW  0u
#define O_POS   3200000u
#define O_EI    3275000u
#define O_ATTR  6475000u
#define O_BATCH 11275000u
// x_bf16 staging: first 6.4M words of the O_EI region (re-zeroed before enc_count/emit)
// new_pos f32[25000*3] lives at out[O_POS] and is read back by enc_emit.

static __device__ __forceinline__ uint_t f2bf(float f) {
    union { float f; uint_t i; } v; v.f = f;
    uint_t x = v.i;
    return (x + 0x7fffu + ((x >> 16) & 1u)) >> 16;  // RNE
}
static __device__ __forceinline__ float bf2f(ushort_t u) {
    union { uint_t i; float f; } v; v.i = ((uint_t)u) << 16; return v.f;
}

// K0: pack x (f32) -> bf16x2 words into the output-staging region.
__global__ void xpack(const float4* __restrict__ x4, uint2* __restrict__ xb2) {
    int i = blockIdx.x * 256 + threadIdx.x;
    if (i >= NN * 32) return;            // 12.8M floats / 4
    float4 v = x4[i];
    uint2 r;
    r.x = f2bf(v.x) | (f2bf(v.y) << 16);
    r.y = f2bf(v.z) | (f2bf(v.w) << 16);
    xb2[i] = r;
}

// K1: M1[j][o] = sum_f Wrow_j[f] * Wg[f][o], emitted directly as bf16.
__global__ void build_m1f(const float* __restrict__ Wconv,
                          const float* __restrict__ Wedge,
                          const float* __restrict__ Wg,
                          ushort_t* __restrict__ m1b) {
    int j = blockIdx.x;   // 0..130
    int o = threadIdx.x;  // 0..127
    const float* wrow = (j < 128) ? (Wconv + j * DINTER + 16)
                                  : (Wedge + (j - 128) * DINTER + 16);
    float acc = 0.f;
    for (int f = 0; f < 128; ++f)
        acc += wrow[f] * Wg[f * 128 + o];
    m1b[j * 128 + o] = (ushort_t)f2bf(acc);
}

// K2a: fused coarse histograms (LDS-aggregated).
// hA2: (src_slice, dst_node >> 9).  hC: src cluster >> 7 (dedupe).
__global__ void edge_hist2(const int* __restrict__ ei,
                           uint_t* __restrict__ bhA2, uint_t* __restrict__ bhC) {
    __shared__ uint_t hA[NBKT2], hC[NBKT];
    int tid = threadIdx.x;
    for (int i = tid; i < NBKT2; i += 256) hA[i] = 0;
    for (int i = tid; i < NBKT; i += 256) hC[i] = 0;
    __syncthreads();
    for (int e = blockIdx.x * 256 + tid; e < EE; e += 256 * 256) {
        uint_t u = (uint_t)ei[e];
        uint_t v = (uint_t)ei[EE + e];
        atomicAdd(&hA[(u / 12500u) * 196u + (v >> 9)], 1u);
        atomicAdd(&hC[u >> 9], 1u);
    }
    __syncthreads();
    for (int i = tid; i < NBKT2; i += 256) if (hA[i]) atomicAdd(&bhA2[i], hA[i]);
    for (int i = tid; i < NBKT; i += 256)  if (hC[i]) atomicAdd(&bhC[i], hC[i]);
}

// Single-block exclusive scan. out[0..n] (out[n]=total), optional copy out2[0..n-1].
__global__ void scan_small(const uint_t* __restrict__ in, uint_t* __restrict__ out,
                           uint_t* __restrict__ out2, int n) {
    __shared__ uint_t part[256];
    int tid = threadIdx.x;
    int per = (n + 255) >> 8;
    int lo = tid * per;
    int hi = lo + per; if (hi > n) hi = n;
    if (lo > n) lo = n;
    uint_t s = 0;
    for (int i = lo; i < hi; ++i) s += in[i];
    part[tid] = s;
    __syncthreads();
    for (int off = 1; off < 256; off <<= 1) {
        uint_t v = (tid >= off) ? part[tid - off] : 0u;
        __syncthreads();
        part[tid] += v;
        __syncthreads();
    }
    uint_t run = part[tid] - s;
    for (int i = lo; i < hi; ++i) {
        out[i] = run;
        if (out2) out2[i] = run;
        run += in[i];
    }
    if (tid == 255) out[n] = run;
}

#define TPB 4096
// K2b: bucket scatter for the reduce. Payload uint4 = {(cl<<17)|src, ea.x, ea.y, ea.z}
// so downstream never gathers ei[] or ea[] (both read COALESCED here).
__global__ void bucket_place_A2(const int* __restrict__ ei, const float* __restrict__ ea,
                                uint_t* __restrict__ bcur, uint4* __restrict__ pk4) {
    __shared__ uint_t hist[NBKT2], gbase[NBKT2], cur[NBKT2];
    int tid = threadIdx.x;
    int t0 = blockIdx.x * TPB;
    int nt = EE - t0; if (nt > TPB) nt = TPB;
    for (int i = tid; i < NBKT2; i += 256) { hist[i] = 0; cur[i] = 0; }
    __syncthreads();
    for (int i = tid; i < nt; i += 256) {
        int e = t0 + i;
        uint_t u = (uint_t)ei[e];
        uint_t v = (uint_t)ei[EE + e];
        atomicAdd(&hist[(u / 12500u) * 196u + (v >> 9)], 1u);
    }
    __syncthreads();
    for (int b = tid; b < NBKT2; b += 256) {
        uint_t h = hist[b];
        if (h) gbase[b] = atomicAdd(&bcur[b], h);
    }
    __syncthreads();
    for (int i = tid; i < nt; i += 256) {
        int e = t0 + i;
        uint_t u = (uint_t)ei[e];
        uint_t v = (uint_t)ei[EE + e];
        uint_t b = (u / 12500u) * 196u + (v >> 9);
        uint_t r = gbase[b] + atomicAdd(&cur[b], 1u);
        uint4 p;
        p.x = (((v >> 2) & 127u) << 17) | u;
        p.y = __float_as_uint(ea[(size_t)e * 3 + 0]);
        p.z = __float_as_uint(ea[(size_t)e * 3 + 1]);
        p.w = __float_as_uint(ea[(size_t)e * 3 + 2]);
        pk4[r] = p;
    }
}

// K2b': dedupe-side bucket scatter; full key (u<<15)|v fits u32, bucket = pk>>22.
__global__ void bucket_place_C(const int* __restrict__ ei, uint_t* __restrict__ bcur,
                               uint_t* __restrict__ pkC) {
    __shared__ uint_t pk[TPB];
    __shared__ uint_t gpk[TPB];
    __shared__ uint_t hist[NBKT], lbase[NBKT], gbase[NBKT], cur[NBKT];
    __shared__ uint_t part[256];
    int tid = threadIdx.x;
    int t0 = blockIdx.x * TPB;
    int nt = EE - t0; if (nt > TPB) nt = TPB;
    for (int i = tid; i < NBKT; i += 256) { hist[i] = 0; cur[i] = 0; }
    __syncthreads();
    for (int i = tid; i < nt; i += 256) {
        int e = t0 + i;
        uint_t u = ((uint_t)ei[e]) >> 2;
        uint_t v = ((uint_t)ei[EE + e]) >> 2;
        uint_t w = (u << 15) | v;
        pk[i] = w;
        atomicAdd(&hist[w >> 22], 1u);
    }
    __syncthreads();
    uint_t h = (tid < NBKT) ? hist[tid] : 0u;
    if (tid < NBKT) gbase[tid] = atomicAdd(&bcur[tid], h);
    part[tid] = h;
    __syncthreads();
    for (int off = 1; off < 256; off <<= 1) {
        uint_t v = (tid >= off) ? part[tid - off] : 0u;
        __syncthreads();
        part[tid] += v;
        __syncthreads();
    }
    if (tid < NBKT) lbase[tid] = part[tid] - h;
    __syncthreads();
    for (int i = tid; i < nt; i += 256) {
        uint_t b = pk[i] >> 22;
        uint_t r = lbase[b] + atomicAdd(&cur[b], 1u);
        gpk[r] = pk[i];
    }
    __syncthreads();
    for (int r = tid; r < nt; r += 256) {
        uint_t b = gpk[r] >> 22;
        pkC[gbase[b] + ((uint_t)r - lbase[b])] = gpk[r];
    }
}

// K2c: in-LDS counting sort of each (slice, dst-coarse) bucket by cluster-local id.
// NEW: (a) sorted KEYS (.x only) written coalesced to pkW (aliases aggb region, dead
// until agg_merge); (b) per-cluster ea sums computed here in-LDS (f32) and written to
// paggw words 64/65 — removes the 36-instr shfl butterfly from the hot reduce kernel.
__global__ void bucket_sort_A2(const uint_t* __restrict__ bbA2, const uint4* __restrict__ pk4,
                               uint_t* __restrict__ pkW, uint_t* __restrict__ paggw,
                               uint_t* __restrict__ offs2) {
    __shared__ uint4 st[2048];                      // 32 KB payload staging
    __shared__ uint_t hist[128], base2[129], cur[128];
    __shared__ uint_t part[256];
    int tid = threadIdx.x, bk = blockIdx.x;
    uint_t s = bbA2[bk], epos = bbA2[bk + 1];
    int n = (int)(epos - s);
    if (n > 2048) n = 2048;   // statistically unreachable; guards LDS bounds
    if (tid < 128) { hist[tid] = 0; cur[tid] = 0; }
    for (int i = tid; i < n; i += 256) st[i] = pk4[s + i];
    __syncthreads();
    for (int i = tid; i < n; i += 256) atomicAdd(&hist[st[i].x >> 17], 1u);
    __syncthreads();
    uint_t h = (tid < 128) ? hist[tid] : 0u;
    part[tid] = h;
    __syncthreads();
    for (int off = 1; off < 256; off <<= 1) {
        uint_t v = (tid >= off) ? part[tid - off] : 0u;
        __syncthreads();
        part[tid] += v;
        __syncthreads();
    }
    int sl = bk / 196, q = bk - sl * 196;
    if (tid < 128) {
        base2[tid] = part[tid] - h;
        int c = q * 128 + tid;
        if (c < CC) offs2[sl * CC + c] = s + base2[tid];
    }
    if (tid == 255) base2[128] = part[255];   // = n
    if (bk == 0 && tid == 0) offs2[8 * CC] = EE;
    __syncthreads();
    for (int i = tid; i < n; i += 256) {
        uint4 p = st[i];
        uint_t d = p.x >> 17;
        uint_t r = base2[d] + atomicAdd(&cur[d], 1u);
        pkW[s + r] = p.x;
    }
    // per-cluster ea sums from LDS (st unmodified); one thread per cluster
    if (tid < 128) {
        int c = q * 128 + tid;
        if (c < CC) {
            uint_t lo2 = base2[tid], hi2 = base2[tid + 1];
            float e0 = 0.f, e1 = 0.f, e2 = 0.f;
            for (uint_t i = lo2; i < hi2; ++i) {
                e0 += __uint_as_float(st[i].y);
                e1 += __uint_as_float(st[i].z);
                e2 += __uint_as_float(st[i].w);
            }
            uint_t kk = (uint_t)sl * CC + (uint_t)c;
            paggw[(size_t)kk * 66 + 64] = f2bf(e0) | (f2bf(e1) << 16);
            paggw[(size_t)kk * 66 + 65] = f2bf(e2);   // slot 131 = 0
        }
    }
}

// K2c': counting-sort each C-bucket by 5-bit sub key ((u>>2)&31), in place, so the
// dedupe kernels read ONLY their own ~256-entry segment.
__global__ void bucket_sort_C(const uint_t* __restrict__ bbC, uint_t* __restrict__ pkC,
                              uint_t* __restrict__ csub) {
    __shared__ uint_t st[8960];                     // 35.8 KB (bucket mean 8192, +8.5 sigma)
    __shared__ uint_t hist[32], base2[32], cur[32];
    __shared__ uint_t part[256];
    int tid = threadIdx.x, bk = blockIdx.x;
    uint_t s = bbC[bk], epos = bbC[bk + 1];
    int n = (int)(epos - s);
    if (n > 8960) n = 8960;
    if (tid < 32) { hist[tid] = 0; cur[tid] = 0; }
    for (int i = tid; i < n; i += 256) st[i] = pkC[s + i];
    __syncthreads();
    for (int i = tid; i < n; i += 256) atomicAdd(&hist[(st[i] >> 17) & 31u], 1u);
    __syncthreads();
    uint_t h = (tid < 32) ? hist[tid] : 0u;
    part[tid] = h;
    __syncthreads();
    for (int off = 1; off < 256; off <<= 1) {
        uint_t v = (tid >= off) ? part[tid - off] : 0u;
        __syncthreads();
        part[tid] += v;
        __syncthreads();
    }
    if (tid < 32) {
        base2[tid] = part[tid] - h;
        csub[bk * 32 + tid] = s + base2[tid];
    }
    if (bk == 0 && tid == 0) csub[NSEG] = EE;
    __syncthreads();
    for (int i = tid; i < n; i += 256) {
        uint_t w = st[i];
        uint_t d = (w >> 17) & 31u;
        uint_t r = base2[d] + atomicAdd(&cur[d], 1u);
        pkC[s + r] = w;
    }
}

// K3: per cluster: new_pos + new_batch straight to out (enc_emit reads out[O_POS]).
__global__ void cluster_pass(const float* __restrict__ pos, const int* __restrict__ batch,
                             float* __restrict__ out) {
    int c = blockIdx.x * 256 + threadIdx.x;
    if (c >= CC) return;
    float px = 0.f, py = 0.f, pz = 0.f;
    for (int j = 0; j < 4; ++j) {
        int n = c * 4 + j;
        px += pos[n * 3 + 0];
        py += pos[n * 3 + 1];
        pz += pos[n * 3 + 2];
    }
    px *= 0.25f; py *= 0.25f; pz *= 0.25f;
    out[O_POS + c * 3 + 0] = px;
    out[O_POS + c * 3 + 1] = py;
    out[O_POS + c * 3 + 2] = pz;
    int b = batch[c * 4];
    b = max(b, batch[c * 4 + 1]);
    b = max(b, batch[c * 4 + 2]);
    b = max(b, batch[c * 4 + 3]);
    out[O_BATCH + c] = (float)b;
}

// K2d: XCD-affine partial reduce, slimmed: pure x-gather. Coalesced u32 key loads
// (was strided uint4 = 4x bytes), no ea accumulation, no shfl-butterfly epilogue
// (ea sums now from bucket_sort_A2). One wave per (slice s, cluster c) segment;
// s = blockIdx&7 pins x-slice s (3.2 MB) to one XCD's L2 (round-5 verified).
__global__ void cluster_reduce4(const uint_t* __restrict__ offs2, const uint_t* __restrict__ pkW,
                                const uint_t* __restrict__ xb, uint_t* __restrict__ paggw) {
    int tid = threadIdx.x;
    int lane = tid & 63;
    int s = blockIdx.x & 7;
    int c = (blockIdx.x >> 3) * 4 + (tid >> 6);     // 0..24999
    uint_t kk = (uint_t)s * CC + (uint_t)c;
    uint_t start = offs2[kk], end = offs2[kk + 1];
    float a0 = 0.f, a1 = 0.f;
    for (uint_t base = start; base < end; base += 64u) {
        uint_t idx = base + (uint_t)lane;
        int nm = (int)min(64u, end - base);
        uint_t w = (idx < end) ? pkW[idx] : 0u;
        for (int j = 0; j < nm; ++j) {
            uint_t wj = (uint_t)__shfl((int)w, j, 64);
            uint_t src = wj & 0x1FFFFu;
            uint_t xv = xb[(size_t)src * 64 + lane];
            a0 += bf2f((ushort_t)(xv & 0xffffu));
            a1 += bf2f((ushort_t)(xv >> 16));
        }
    }
    paggw[(size_t)kk * 66 + lane] = f2bf(a0) | (f2bf(a1) << 16);
}

// K2e: fold 8 slice-partials -> aggb (f32 sum of bf16 partials, bf16 out).
__global__ void agg_merge(const uint_t* __restrict__ paggw, uint_t* __restrict__ aggw) {
    int j = blockIdx.x * 256 + threadIdx.x;
    if (j >= 1650000) return;
    float lo = 0.f, hi = 0.f;
    #pragma unroll
    for (int s = 0; s < 8; ++s) {
        uint_t w = paggw[(size_t)s * 1650000u + (uint_t)j];
        lo += bf2f((ushort_t)(w & 0xffffu));
        hi += bf2f((ushort_t)(w >> 16));
    }
    aggw[j] = f2bf(lo) | (f2bf(hi) << 16);
}

// K4: x_new[c][o] = 0.25 * sum_{j<131} aggb[c][j] * M1[j][o].
#define GEMM_CPB 32   // clusters per block = 4 iterations of 8
__global__ void gemm_tiled(const ushort_t* __restrict__ aggb, const ushort_t* __restrict__ m1b,
                           float* __restrict__ out) {
    __shared__ ushort_t m1s[131 * 128];            // 33.5 KB bf16
    __shared__ __align__(16) float srowT[132][8];  // 4.2 KB, [j][cluster-in-group]
    int tid = threadIdx.x;
    {
        const uint_t* m1w = (const uint_t*)m1b;
        uint_t* m1sw = (uint_t*)m1s;
        for (int i = tid; i < 131 * 64; i += 256) m1sw[i] = m1w[i];
    }
    int o = tid & 127, half = tid >> 7;
    int c0b = blockIdx.x * GEMM_CPB;
    const uint_t* aggw = (const uint_t*)aggb;      // row = 66 u32 words
    for (int it = 0; it < GEMM_CPB / 8; ++it) {
        int c0 = c0b + it * 8;
        __syncthreads();   // previous-iteration readers done before overwrite
        for (int i = tid; i < 528; i += 256) {
            int cg = i / 66, rem = i - cg * 66;
            int c = c0 + cg;
            uint_t w = (c < CC) ? aggw[(size_t)c * 66 + rem] : 0u;
            srowT[rem * 2][cg]     = bf2f((ushort_t)(w & 0xffffu));
            srowT[rem * 2 + 1][cg] = bf2f((ushort_t)(w >> 16));
        }
        __syncthreads();   // also covers m1s staging on it==0
        float acc0 = 0.f, acc1 = 0.f, acc2 = 0.f, acc3 = 0.f;
        #pragma unroll 4
        for (int j = 0; j < 131; ++j) {
            float m = bf2f(m1s[j * 128 + o]);
            float4 s = *(const float4*)&srowT[j][half * 4];  // broadcast within wave
            acc0 += s.x * m;
            acc1 += s.y * m;
            acc2 += s.z * m;
            acc3 += s.w * m;
        }
        int cb = c0 + half * 4;
        if (cb + 0 < CC) out[O_XNEW + (size_t)(cb + 0) * 128 + o] = 0.25f * acc0;
        if (cb + 1 < CC) out[O_XNEW + (size_t)(cb + 1) * 128 + o] = 0.25f * acc1;
        if (cb + 2 < CC) out[O_XNEW + (size_t)(cb + 2) * 128 + o] = 0.25f * acc2;
        if (cb + 3 < CC) out[O_XNEW + (size_t)(cb + 3) * 128 + o] = 0.25f * acc3;
    }
}

// K6a: per-segment dedupe: read OWN ~256-entry segment, 12.5 KB LDS bitmap
// (4 u-clusters x 25000 v bits), block scan, emit deduped keys (le, rank-dense)
// to kbuf[bid*KCAP] + count. Bitmap built ONCE (emit kernel reads keys, not pkC).
__global__ void enc_count(const uint_t* __restrict__ csub, const uint_t* __restrict__ pkC,
                          uint_t* __restrict__ bcnt, uint_t* __restrict__ kbuf) {
    __shared__ uint_t bmp[3125];
    __shared__ uint_t sh[256];
    int tid = threadIdx.x, bid = blockIdx.x;
    uint_t s = csub[bid], epos = csub[bid + 1];
    int n = (int)(epos - s);
    for (int i = tid; i < 3125; i += 256) bmp[i] = 0;
    __syncthreads();
    for (int i = tid; i < n; i += 256) {
        uint_t w = pkC[s + i];
        uint_t le = ((w >> 15) & 3u) * 25000u + (w & 32767u);
        atomicOr(&bmp[le >> 5], 1u << (le & 31u));
    }
    __syncthreads();
    int lo = tid * 13, hi = lo + 13;
    if (lo > 3125) lo = 3125;
    if (hi > 3125) hi = 3125;
    uint_t mine = 0;
    for (int i = lo; i < hi; ++i) mine += __popc(bmp[i]);
    sh[tid] = mine;
    __syncthreads();
    for (int off = 1; off < 256; off <<= 1) {
        uint_t v = (tid >= off) ? sh[tid - off] : 0u;
        __syncthreads();
        sh[tid] += v;
        __syncthreads();
    }
    uint_t r = sh[tid] - mine;
    uint_t kb = (uint_t)bid * KCAP;
    for (int i = lo; i < hi; ++i) {
        uint_t bits = bmp[i];
        while (bits) {
            int b = __builtin_ctz(bits);
            bits &= bits - 1u;
            if (r < KCAP) kbuf[kb + r] = (uint_t)i * 32u + (uint_t)b;
            r++;
        }
    }
    if (tid == 255) bcnt[bid] = min(sh[255], (uint_t)KCAP);
}

// K6b: decode dense keys, write u/v COALESCED + attrs (np gathers are L2-resident).
// Global order: bid asc (= u-group asc), key asc within (= (u&3, v) asc) ->
// ascending enc, identical to jnp.unique output order.
__global__ void enc_emit(const uint_t* __restrict__ ebase, const uint_t* __restrict__ kbuf,
                         float* __restrict__ out) {
    int tid = threadIdx.x, bid = blockIdx.x;
    uint_t g0 = ebase[bid], g1 = ebase[bid + 1];
    int cnt = (int)(g1 - g0);
    const float* np = out + O_POS;
    uint_t ubase = ((uint_t)(bid >> 5)) * 128u + ((uint_t)(bid & 31)) * 4u;
    uint_t kb = (uint_t)bid * KCAP;
    for (int r = tid; r < cnt; r += 256) {
        uint_t le = kbuf[kb + r];
        uint_t uo = le / 25000u;
        uint_t v = le - uo * 25000u;
        uint_t u = ubase + uo;
        uint_t rank = g0 + (uint_t)r;
        out[O_EI + rank] = (float)u;
        out[O_EI + EE + rank] = (float)v;
        out[O_ATTR + (size_t)rank * 3 + 0] = np[v * 3 + 0] - np[u * 3 + 0];
        out[O_ATTR + (size_t)rank * 3 + 1] = np[v * 3 + 1] - np[u * 3 + 1];
        out[O_ATTR + (size_t)rank * 3 + 2] = np[v * 3 + 2] - np[u * 3 + 2];
    }
}

extern "C" void kernel_launch(void* const* d_in, const int* in_sizes, int n_in,
                              void* d_out, int out_size, void* d_ws, size_t ws_size,
                              hipStream_t stream) {
    const float* x     = (const float*)d_in[0];
    const float* pos   = (const float*)d_in[1];
    const int*   ei    = (const int*)d_in[2];
    const float* ea    = (const float*)d_in[3];
    const int*   batch = (const int*)d_in[4];
    const float* Wconv = (const float*)d_in[5];
    const float* Wedge = (const float*)d_in[6];
    // d_in[7] = D_bloom: dead (bloom_pos never reaches an output)
    const float* Wg    = (const float*)d_in[8];
    // d_in[9] = W_gattr: contribution cancels exactly within each cluster

    float*  out = (float*)d_out;
    uint_t* ws  = (uint_t*)d_ws;

    if (ws_size < (size_t)WS_WORDS * 4) return;

    ushort_t* m1b    = (ushort_t*)(ws + W_M1B);
    ushort_t* aggb   = (ushort_t*)(ws + W_AGGB);
    uint_t*   pkW    = ws + W_AGGB;             // sorted keys alias aggb (dead until agg_merge)
    uint_t*   paggw  = ws + W_PAGG;
    uint4*    pk4    = (uint4*)(ws + W_PKA4);
    uint_t*   pkC    = ws + W_PKC;
    uint_t*   offs2  = ws + W_OFFS2;
    uint_t*   bhA2   = ws + W_BHA2;
    uint_t*   bhC    = ws + W_BHC;
    uint_t*   bbA2   = ws + W_BBA2;
    uint_t*   bcurA2 = ws + W_BCURA2;
    uint_t*   bbC    = ws + W_BBC;
    uint_t*   bcurC  = ws + W_BCURC;
    uint_t*   xb     = (uint_t*)(out + O_EI);   // 6.4M-word bf16-x staging in out region
    // dead-region reuse (valid after bucket_sort_A2 / agg_merge):
    uint_t*   csub   = ws + W_PKA4;             // u32 [NSEG+1]
    uint_t*   bcnt2  = ws + W_PKA4 + 8192u;     // u32 [NSEG]
    uint_t*   ebase2 = ws + W_PKA4 + 16384u;    // u32 [NSEG+1]
    uint_t*   kbuf   = ws + W_PAGG;             // u32 [NSEG*KCAP] = 6.42M <= 13.2M

    hipMemsetAsync(bhA2, 0, (size_t)(NBKT2 + NBKT) * 4, stream);   // bhA2 + bhC contiguous

    xpack<<<dim3(12500), dim3(256), 0, stream>>>((const float4*)x, (uint2*)xb);
    build_m1f<<<dim3(131), dim3(128), 0, stream>>>(Wconv, Wedge, Wg, m1b);
    edge_hist2<<<dim3(256), dim3(256), 0, stream>>>(ei, bhA2, bhC);
    scan_small<<<dim3(1), dim3(256), 0, stream>>>(bhA2, bbA2, bcurA2, NBKT2);
    scan_small<<<dim3(1), dim3(256), 0, stream>>>(bhC, bbC, bcurC, NBKT);
    bucket_place_A2<<<dim3((EE + TPB - 1) / TPB), dim3(256), 0, stream>>>(ei, ea, bcurA2, pk4);
    bucket_place_C<<<dim3((EE + TPB - 1) / TPB), dim3(256), 0, stream>>>(ei, bcurC, pkC);
    bucket_sort_A2<<<dim3(NBKT2), dim3(256), 0, stream>>>(bbA2, pk4, pkW, paggw, offs2);
    cluster_pass<<<dim3(98), dim3(256), 0, stream>>>(pos, batch, out);
    cluster_reduce4<<<dim3(50000), dim3(256), 0, stream>>>(offs2, pkW, xb, paggw);
    agg_merge<<<dim3(6446), dim3(256), 0, stream>>>(paggw, (uint_t*)aggb);
    gemm_tiled<<<dim3((CC + GEMM_CPB - 1) / GEMM_CPB), dim3(256), 0, stream>>>(aggb, m1b, out);
    // x_bf16 staging no longer needed: zero the EI/ATTR region (incl. padding tail)
    hipMemsetAsync((char*)d_out + (size_t)O_EI * 4, 0, (size_t)(3200000 + 4800000) * 4, stream);
    bucket_sort_C<<<dim3(NBKT), dim3(256), 0, stream>>>(bbC, pkC, csub);
    enc_count<<<dim3(NSEG), dim3(256), 0, stream>>>(csub, pkC, bcnt2, kbuf);
    scan_small<<<dim3(1), dim3(256), 0, stream>>>(bcnt2, ebase2, (uint_t*)0, NSEG);
    enc_emit<<<dim3(NSEG), dim3(256), 0, stream>>>(ebase2, kbuf, out);
}